// Round 2
// baseline (17139.784 us; speedup 1.0000x reference)
//
#include <hip/hip_runtime.h>
#include <hip/hip_bf16.h>
#include <float.h>
#include <math.h>

// ---------------- problem constants ----------------
#define BB 2
#define SS 1024
#define LL 767
#define TT 1536          // 2*(LL+1)
#define DD 256
#define HH 8
#define DHD 2048
#define INNER_ 16384
#define VV 25426
#define CLS_TOK 25426
#define MASK_TOKEN 25428
#define ROWS (BB*TT)     // 3072
#define SROWS (BB*SS)    // 2048

// ---------------- small helper kernels ----------------

__global__ __launch_bounds__(256) void embed_kernel(
    const int* __restrict__ t1, const int* __restrict__ t2,
    const float* __restrict__ emb, float* __restrict__ x,
    unsigned char* __restrict__ tgt_pad)
{
    int t = blockIdx.x, b = blockIdx.y, d = threadIdx.x;
    int raw;
    if (t == 0)            raw = CLS_TOK;
    else if (t <= LL)      raw = t1[b * LL + (t - 1)];
    else if (t == LL + 1)  raw = CLS_TOK;
    else                   raw = t2[b * LL + (t - LL - 2)];
    int id = (raw == 0 || raw == MASK_TOKEN) ? MASK_TOKEN : raw;
    int i = d >> 1;
    // div = exp(-(2i) * ln(10000)/256)
    float ang = (float)t * expf(-0.03597789208f * (float)(2 * i));
    float pe = (d & 1) ? cosf(ang) : sinf(ang);
    x[((long long)(b * TT + t)) * DD + d] = 2.f * emb[(long long)id * DD + d] + pe;
    if (d == 0) tgt_pad[b * TT + t] = (raw == 0) ? 1 : 0;
}

__global__ __launch_bounds__(256) void srcmask_kernel(
    const int* __restrict__ src, unsigned char* __restrict__ m)
{
    int i = blockIdx.x * 256 + threadIdx.x;
    if (i < SROWS) m[i] = (src[i] == 0) ? 1 : 0;
}

__global__ __launch_bounds__(256) void rowmap_kernel(int* __restrict__ rm)
{
    int r = blockIdx.x * 256 + threadIdx.x;
    if (r >= ROWS) return;
    int b = r / TT, t = r % TT;
    rm[r] = (t == 0) ? -1 : (b * (TT - 1) + t - 1);
}

__global__ __launch_bounds__(256) void copycls_kernel(
    const float* __restrict__ x, float* __restrict__ out2)
{
    int b = blockIdx.x, d = threadIdx.x;
    out2[b * DD + d] = x[(long long)b * TT * DD + d];
}

// ---------------- big SGEMM: 128x128 tile, BK=8, 8x8 per thread ----------------
// C[M,N] = alpha * A[M,K] * B (+bias), B row-major [K,N] (TRANSB=0) or [N,K] (TRANSB=1).
// Requires M%128==0, K%8==0, lda%4==0. N edge handled (scalar B path + store guard).
// Optional rowmap: output row r goes to rowmap[r] (skipped if negative).
template<int TRANSB>
__global__ __launch_bounds__(256) void sgemm_big(
    const float* __restrict__ A, int lda, long long sA,
    const float* __restrict__ Bm, int ldb, long long sB,
    float* __restrict__ C, int ldc, long long sC,
    int M, int N, int K, float alpha,
    const float* __restrict__ bias, const int* __restrict__ rowmap)
{
    __shared__ float As[8][128];
    __shared__ float Bs[8][128];
    const int tid = threadIdx.x;
    const int tx = tid & 15, ty = tid >> 4;
    const int m0 = blockIdx.x * 128;
    const int n0 = blockIdx.y * 128;
    A  += (long long)blockIdx.z * sA;
    Bm += (long long)blockIdx.z * sB;
    C  += (long long)blockIdx.z * sC;

    const int ar = tid >> 1, ak = (tid & 1) * 4;          // A loader
    const int bnn_k = tid >> 5, bnn_n = (tid & 31) * 4;   // B loader (NN)
    const int bnt_n = tid >> 1, bnt_k = (tid & 1) * 4;    // B loader (NT)
    const bool bfull = TRANSB ? true : (((ldb & 3) == 0) && (n0 + 128 <= N));

    float acc[8][8];
#pragma unroll
    for (int i = 0; i < 8; ++i)
#pragma unroll
        for (int j = 0; j < 8; ++j) acc[i][j] = 0.f;

    for (int kt = 0; kt < K; kt += 8) {
        {
            const float4 va = *reinterpret_cast<const float4*>(
                A + (long long)(m0 + ar) * lda + (kt + ak));
            As[ak + 0][ar] = va.x; As[ak + 1][ar] = va.y;
            As[ak + 2][ar] = va.z; As[ak + 3][ar] = va.w;
        }
        if (TRANSB) {
            const float4 vb = *reinterpret_cast<const float4*>(
                Bm + (long long)(n0 + bnt_n) * ldb + (kt + bnt_k));
            Bs[bnt_k + 0][bnt_n] = vb.x; Bs[bnt_k + 1][bnt_n] = vb.y;
            Bs[bnt_k + 2][bnt_n] = vb.z; Bs[bnt_k + 3][bnt_n] = vb.w;
        } else if (bfull) {
            const float4 vb = *reinterpret_cast<const float4*>(
                Bm + (long long)(kt + bnn_k) * ldb + (n0 + bnn_n));
            *reinterpret_cast<float4*>(&Bs[bnn_k][bnn_n]) = vb;
        } else {
            const float* srcp = Bm + (long long)(kt + bnn_k) * ldb;
#pragma unroll
            for (int j = 0; j < 4; ++j) {
                int col = n0 + bnn_n + j;
                Bs[bnn_k][bnn_n + j] = (col < N) ? srcp[col] : 0.f;
            }
        }
        __syncthreads();
#pragma unroll
        for (int k = 0; k < 8; ++k) {
            float a[8], b[8];
#pragma unroll
            for (int i = 0; i < 8; ++i) a[i] = As[k][ty + i * 16];
#pragma unroll
            for (int j = 0; j < 8; ++j) b[j] = Bs[k][tx + j * 16];
#pragma unroll
            for (int i = 0; i < 8; ++i)
#pragma unroll
                for (int j = 0; j < 8; ++j)
                    acc[i][j] = fmaf(a[i], b[j], acc[i][j]);
        }
        __syncthreads();
    }

#pragma unroll
    for (int i = 0; i < 8; ++i) {
        int r = m0 + ty + i * 16;
        int rm = rowmap ? rowmap[r] : r;
        if (rm < 0) continue;
        float* crow = C + (long long)rm * ldc;
#pragma unroll
        for (int j = 0; j < 8; ++j) {
            int n = n0 + tx + j * 16;
            if (n < N) {
                float v = acc[i][j] * alpha;
                if (bias) v += bias[n];
                crow[n] = v;
            }
        }
    }
}

// ---------------- small SGEMM: 64x64 tile, BK=16, 4x4 per thread ----------------
// mode: 0 = store, 1 = store+bias, 2 = store+bias+exact-GELU, 3 = atomicAdd (split-K)
// Requires M%64==0, N%64==0, (K/gridDim.z)%16==0, lda%4==0, ldb%4==0.
__global__ __launch_bounds__(256) void sgemm_small(
    const float* __restrict__ A, int lda,
    const float* __restrict__ Bm, int ldb,
    float* __restrict__ C, int ldc,
    int M, int N, int K, int mode, const float* __restrict__ bias)
{
    __shared__ float As[16][64];
    __shared__ float Bs[16][64];
    const int tid = threadIdx.x;
    const int tx = tid & 15, ty = tid >> 4;
    const int m0 = blockIdx.x * 64;
    const int n0 = blockIdx.y * 64;
    const int Ks = K / gridDim.z;
    const int kb = blockIdx.z * Ks;
    const int ar = tid >> 2, ak = (tid & 3) * 4;
    const int bk = tid >> 4, bn = (tid & 15) * 4;

    float acc[4][4];
#pragma unroll
    for (int i = 0; i < 4; ++i)
#pragma unroll
        for (int j = 0; j < 4; ++j) acc[i][j] = 0.f;

    for (int kt = kb; kt < kb + Ks; kt += 16) {
        {
            const float4 va = *reinterpret_cast<const float4*>(
                A + (long long)(m0 + ar) * lda + (kt + ak));
            As[ak + 0][ar] = va.x; As[ak + 1][ar] = va.y;
            As[ak + 2][ar] = va.z; As[ak + 3][ar] = va.w;
        }
        {
            const float4 vb = *reinterpret_cast<const float4*>(
                Bm + (long long)(kt + bk) * ldb + (n0 + bn));
            *reinterpret_cast<float4*>(&Bs[bk][bn]) = vb;
        }
        __syncthreads();
#pragma unroll
        for (int k = 0; k < 16; ++k) {
            float a[4], b[4];
#pragma unroll
            for (int i = 0; i < 4; ++i) a[i] = As[k][ty + i * 16];
#pragma unroll
            for (int j = 0; j < 4; ++j) b[j] = Bs[k][tx + j * 16];
#pragma unroll
            for (int i = 0; i < 4; ++i)
#pragma unroll
                for (int j = 0; j < 4; ++j)
                    acc[i][j] = fmaf(a[i], b[j], acc[i][j]);
        }
        __syncthreads();
    }

#pragma unroll
    for (int i = 0; i < 4; ++i) {
        int r = m0 + ty + i * 16;
        float* crow = C + (long long)r * ldc;
#pragma unroll
        for (int j = 0; j < 4; ++j) {
            int n = n0 + tx + j * 16;
            float v = acc[i][j];
            if (mode == 3) {
                atomicAdd(&crow[n], v);
            } else {
                if (mode >= 1) v += bias[n];
                if (mode == 2) v = 0.5f * v * (1.f + erff(v * 0.70710678118f));
                crow[n] = v;
            }
        }
    }
}

// ---------------- masked row softmax (row length = CNT*256) ----------------
template<int CNT>
__global__ __launch_bounds__(256) void softmax_rows(
    float* __restrict__ S, const unsigned char* __restrict__ mask)
{
    __shared__ float red[4];
    const int b = blockIdx.y;
    float* p = S + ((long long)b * TT + blockIdx.x) * (CNT * 256);
    const unsigned char* mk = mask + (long long)b * (CNT * 256);
    const int tid = threadIdx.x;

    float v[CNT];
    float mx = -FLT_MAX;
#pragma unroll
    for (int c = 0; c < CNT; ++c) {
        int j = (c << 8) + tid;
        float s = p[j];
        if (mk[j]) s = -FLT_MAX;
        v[c] = s;
        mx = fmaxf(mx, s);
    }
#pragma unroll
    for (int off = 32; off > 0; off >>= 1) mx = fmaxf(mx, __shfl_down(mx, off));
    if ((tid & 63) == 0) red[tid >> 6] = mx;
    __syncthreads();
    mx = fmaxf(fmaxf(red[0], red[1]), fmaxf(red[2], red[3]));
    __syncthreads();

    float sum = 0.f;
#pragma unroll
    for (int c = 0; c < CNT; ++c) {
        float e = expf(v[c] - mx);
        v[c] = e;
        sum += e;
    }
#pragma unroll
    for (int off = 32; off > 0; off >>= 1) sum += __shfl_down(sum, off);
    if ((tid & 63) == 0) red[tid >> 6] = sum;
    __syncthreads();
    sum = red[0] + red[1] + red[2] + red[3];
    float inv = 1.f / sum;
#pragma unroll
    for (int c = 0; c < CNT; ++c) p[(c << 8) + tid] = v[c] * inv;
}

// ---------------- residual + LayerNorm (in place on x) ----------------
__global__ __launch_bounds__(256) void ln_kernel(
    float* __restrict__ x, const float* __restrict__ a,
    const float* __restrict__ abias,
    const float* __restrict__ g, const float* __restrict__ be)
{
    __shared__ float red[4];
    const long long r = blockIdx.x;
    const int d = threadIdx.x;
    const long long idx = r * DD + d;
    float v = x[idx] + a[idx];
    if (abias) v += abias[d];

    float s = v;
#pragma unroll
    for (int off = 32; off > 0; off >>= 1) s += __shfl_down(s, off);
    if ((d & 63) == 0) red[d >> 6] = s;
    __syncthreads();
    float mean = (red[0] + red[1] + red[2] + red[3]) * (1.f / DD);
    __syncthreads();

    float df = v - mean;
    float s2 = df * df;
#pragma unroll
    for (int off = 32; off > 0; off >>= 1) s2 += __shfl_down(s2, off);
    if ((d & 63) == 0) red[d >> 6] = s2;
    __syncthreads();
    float var = (red[0] + red[1] + red[2] + red[3]) * (1.f / DD);

    x[idx] = df / sqrtf(var + 1e-5f) * g[d] + be[d];
}

// ---------------- launch ----------------
extern "C" void kernel_launch(void* const* d_in, const int* in_sizes, int n_in,
                              void* d_out, int out_size, void* d_ws, size_t ws_size,
                              hipStream_t stream)
{
    const int*   src_ids = (const int*)d_in[0];
    const int*   t1      = (const int*)d_in[1];
    const int*   t2      = (const int*)d_in[2];
    // d_in[3] original_lens: unused by reference
    const float* enc  = (const float*)d_in[4];
    const float* emb  = (const float*)d_in[5];
    const float* Wq_s = (const float*)d_in[6];
    const float* Wk_s = (const float*)d_in[7];
    const float* Wv_s = (const float*)d_in[8];
    const float* Wo_s = (const float*)d_in[9];
    const float* bo_s = (const float*)d_in[10];
    const float* Wq_c = (const float*)d_in[11];
    const float* Wk_c = (const float*)d_in[12];
    const float* Wv_c = (const float*)d_in[13];
    const float* Wo_c = (const float*)d_in[14];
    const float* bo_c = (const float*)d_in[15];
    const float* W1   = (const float*)d_in[16];
    const float* b1   = (const float*)d_in[17];
    const float* W2   = (const float*)d_in[18];
    const float* b2   = (const float*)d_in[19];
    const float* g1   = (const float*)d_in[20];
    const float* g2   = (const float*)d_in[21];
    const float* g3   = (const float*)d_in[22];
    const float* be1  = (const float*)d_in[23];
    const float* be2  = (const float*)d_in[24];
    const float* be3  = (const float*)d_in[25];
    const float* Wfc  = (const float*)d_in[26];
    const float* bfc  = (const float*)d_in[27];

    // workspace layout (floats)
    float* ws   = (float*)d_ws;
    float* x    = ws;                       // ROWS*DD          = 786432
    float* aout = x    + 786432;            // ROWS*DD
    float* Qh   = aout + 786432;            // ROWS*DHD         = 6291456
    float* Kh   = Qh   + 6291456;           // max(ROWS,SROWS)*DHD
    float* Vh   = Kh   + 6291456;
    float* Oh   = Vh   + 6291456;
    float* sim  = Oh   + 6291456;           // BB*TT*TT         = 4718592
    unsigned char* tgtpad = (unsigned char*)(sim + 4718592);
    unsigned char* srcpad = tgtpad + ROWS;
    int* rowmap = (int*)(srcpad + SROWS);

    embed_kernel<<<dim3(TT, BB), 256, 0, stream>>>(t1, t2, emb, x, tgtpad);
    srcmask_kernel<<<dim3(SROWS / 256), 256, 0, stream>>>(src_ids, srcpad);
    rowmap_kernel<<<dim3(ROWS / 256), 256, 0, stream>>>(rowmap);

    const float scale = 0.022097086912079608f;  // DH^-0.5

    // ---------- self attention ----------
    hipMemsetAsync(aout, 0, (size_t)ROWS * DD * sizeof(float), stream);
    for (int h = 0; h < HH; ++h) {
        sgemm_big<0><<<dim3(ROWS/128, DHD/128, 1), 256, 0, stream>>>(
            x, DD, 0, Wq_s + h * DHD, INNER_, 0, Qh, DHD, 0,
            ROWS, DHD, DD, 1.f, nullptr, nullptr);
        sgemm_big<0><<<dim3(ROWS/128, DHD/128, 1), 256, 0, stream>>>(
            x, DD, 0, Wk_s + h * DHD, INNER_, 0, Kh, DHD, 0,
            ROWS, DHD, DD, 1.f, nullptr, nullptr);
        sgemm_big<0><<<dim3(ROWS/128, DHD/128, 1), 256, 0, stream>>>(
            x, DD, 0, Wv_s + h * DHD, INNER_, 0, Vh, DHD, 0,
            ROWS, DHD, DD, 1.f, nullptr, nullptr);
        sgemm_big<1><<<dim3(TT/128, TT/128, BB), 256, 0, stream>>>(
            Qh, DHD, (long long)TT * DHD, Kh, DHD, (long long)TT * DHD,
            sim, TT, (long long)TT * TT,
            TT, TT, DHD, scale, nullptr, nullptr);
        softmax_rows<6><<<dim3(TT, BB), 256, 0, stream>>>(sim, tgtpad);
        sgemm_big<0><<<dim3(TT/128, DHD/128, BB), 256, 0, stream>>>(
            sim, TT, (long long)TT * TT, Vh, DHD, (long long)TT * DHD,
            Oh, DHD, (long long)TT * DHD,
            TT, DHD, TT, 1.f, nullptr, nullptr);
        sgemm_small<<<dim3(ROWS/64, DD/64, 4), 256, 0, stream>>>(
            Oh, DHD, Wo_s + (long long)h * DHD * DD, DD, aout, DD,
            ROWS, DD, DHD, 3, nullptr);
    }
    ln_kernel<<<dim3(ROWS), 256, 0, stream>>>(x, aout, bo_s, g1, be1);

    // ---------- cross attention ----------
    hipMemsetAsync(aout, 0, (size_t)ROWS * DD * sizeof(float), stream);
    for (int h = 0; h < HH; ++h) {
        sgemm_big<0><<<dim3(ROWS/128, DHD/128, 1), 256, 0, stream>>>(
            x, DD, 0, Wq_c + h * DHD, INNER_, 0, Qh, DHD, 0,
            ROWS, DHD, DD, 1.f, nullptr, nullptr);
        sgemm_big<0><<<dim3(SROWS/128, DHD/128, 1), 256, 0, stream>>>(
            enc, DD, 0, Wk_c + h * DHD, INNER_, 0, Kh, DHD, 0,
            SROWS, DHD, DD, 1.f, nullptr, nullptr);
        sgemm_big<0><<<dim3(SROWS/128, DHD/128, 1), 256, 0, stream>>>(
            enc, DD, 0, Wv_c + h * DHD, INNER_, 0, Vh, DHD, 0,
            SROWS, DHD, DD, 1.f, nullptr, nullptr);
        sgemm_big<1><<<dim3(TT/128, SS/128, BB), 256, 0, stream>>>(
            Qh, DHD, (long long)TT * DHD, Kh, DHD, (long long)SS * DHD,
            sim, SS, (long long)TT * SS,
            TT, SS, DHD, scale, nullptr, nullptr);
        softmax_rows<4><<<dim3(TT, BB), 256, 0, stream>>>(sim, srcpad);
        sgemm_big<0><<<dim3(TT/128, DHD/128, BB), 256, 0, stream>>>(
            sim, SS, (long long)TT * SS, Vh, DHD, (long long)SS * DHD,
            Oh, DHD, (long long)TT * DHD,
            TT, DHD, SS, 1.f, nullptr, nullptr);
        sgemm_small<<<dim3(ROWS/64, DD/64, 4), 256, 0, stream>>>(
            Oh, DHD, Wo_c + (long long)h * DHD * DD, DD, aout, DD,
            ROWS, DD, DHD, 3, nullptr);
    }
    ln_kernel<<<dim3(ROWS), 256, 0, stream>>>(x, aout, bo_c, g2, be2);

    // ---------- FFN (D->D->D, exact GELU) ----------
    float* h1 = Qh;
    sgemm_small<<<dim3(ROWS/64, DD/64, 1), 256, 0, stream>>>(
        x, DD, W1, DD, h1, DD, ROWS, DD, DD, 2, b1);
    sgemm_small<<<dim3(ROWS/64, DD/64, 1), 256, 0, stream>>>(
        h1, DD, W2, DD, aout, DD, ROWS, DD, DD, 0, nullptr);
    ln_kernel<<<dim3(ROWS), 256, 0, stream>>>(x, aout, b2, g3, be3);

    // ---------- logits (row-mapped store drops t==0 rows) ----------
    sgemm_big<0><<<dim3(ROWS/128, (VV + 127) / 128, 1), 256, 0, stream>>>(
        x, DD, 0, Wfc, VV, 0, (float*)d_out, VV, 0,
        ROWS, VV, DD, 1.f, bfc, rowmap);

    // ---------- second output: x[:,0,:] ----------
    copycls_kernel<<<dim3(BB), 256, 0, stream>>>(
        x, (float*)d_out + (long long)BB * (TT - 1) * VV);
}

// Round 4
// 2471.680 us; speedup vs baseline: 6.9345x; 6.9345x over previous
//
#include <hip/hip_runtime.h>
#include <hip/hip_bf16.h>
#include <float.h>
#include <math.h>

// ---------------- problem constants ----------------
#define BB 2
#define SS 1024
#define LL 767
#define TT 1536          // 2*(LL+1)
#define DD 256
#define HH 8
#define DHD 2048
#define INNER_ 16384
#define VV 25426
#define VPAD 25472       // VV padded to multiple of 128
#define CLS_TOK 25426
#define MASK_TOKEN 25428
#define ROWS (BB*TT)     // 3072
#define SROWS (BB*SS)    // 2048

typedef __attribute__((ext_vector_type(8))) __bf16 bf16x8;
typedef __attribute__((ext_vector_type(4))) float f32x4;

__device__ __forceinline__ unsigned short f2bu(float f) {
    union { float f; unsigned u; } v; v.f = f;
    unsigned r = v.u + 0x7fff + ((v.u >> 16) & 1);
    return (unsigned short)(r >> 16);
}
__device__ __forceinline__ float bu2f(unsigned short u) {
    union { unsigned u; float f; } v; v.u = ((unsigned)u) << 16;
    return v.f;
}

__device__ __forceinline__ void gload16(const void* g, void* l) {
    __builtin_amdgcn_global_load_lds(
        (const __attribute__((address_space(1))) void*)g,
        (__attribute__((address_space(3))) void*)l, 16, 0, 0);
}

// ---------------- small helper kernels ----------------

__global__ __launch_bounds__(256) void embed_kernel(
    const int* __restrict__ t1, const int* __restrict__ t2,
    const float* __restrict__ emb, float* __restrict__ x,
    unsigned short* __restrict__ xb, unsigned char* __restrict__ tgt_pad)
{
    int t = blockIdx.x, b = blockIdx.y, d = threadIdx.x;
    int raw;
    if (t == 0)            raw = CLS_TOK;
    else if (t <= LL)      raw = t1[b * LL + (t - 1)];
    else if (t == LL + 1)  raw = CLS_TOK;
    else                   raw = t2[b * LL + (t - LL - 2)];
    int id = (raw == 0 || raw == MASK_TOKEN) ? MASK_TOKEN : raw;
    int i = d >> 1;
    float ang = (float)t * expf(-0.03597789208f * (float)(2 * i));
    float pe = (d & 1) ? cosf(ang) : sinf(ang);
    float val = 2.f * emb[(long long)id * DD + d] + pe;
    long long idx = ((long long)(b * TT + t)) * DD + d;
    x[idx] = val;
    xb[idx] = f2bu(val);
    if (d == 0) tgt_pad[b * TT + t] = (raw == 0) ? 1 : 0;
}

__global__ __launch_bounds__(256) void srcmask_kernel(
    const int* __restrict__ src, unsigned char* __restrict__ m)
{
    int i = blockIdx.x * 256 + threadIdx.x;
    if (i < SROWS) m[i] = (src[i] == 0) ? 1 : 0;
}

__global__ __launch_bounds__(256) void rowmap_kernel(int* __restrict__ rm)
{
    int r = blockIdx.x * 256 + threadIdx.x;
    if (r >= ROWS) return;
    int b = r / TT, t = r % TT;
    rm[r] = (t == 0) ? -1 : (b * (TT - 1) + t - 1);
}

__global__ __launch_bounds__(256) void copycls_kernel(
    const float* __restrict__ x, float* __restrict__ out2)
{
    int b = blockIdx.x, d = threadIdx.x;
    out2[b * DD + d] = x[(long long)b * TT * DD + d];
}

__global__ __launch_bounds__(256) void conv_bf16(
    const float* __restrict__ in, unsigned short* __restrict__ out, int n)
{
    int i = blockIdx.x * 256 + threadIdx.x;
    if (i < n) out[i] = f2bu(in[i]);
}

// transpose + convert: out[n][k] = bf16(in[k][n]); in [R][Cin] f32, out [Nout][R] bf16.
// Zero-pads rows n in [Cin, Nout). R % 32 == 0, Nout % 32 == 0.
__global__ __launch_bounds__(256) void transpose_conv(
    const float* __restrict__ in, unsigned short* __restrict__ out,
    int R, int Cin, int Nout)
{
    __shared__ float t[32][33];
    int k0 = blockIdx.x * 32, n0 = blockIdx.y * 32;
#pragma unroll
    for (int i = 0; i < 4; ++i) {
        int k = k0 + threadIdx.y + i * 8;
        int n = n0 + threadIdx.x;
        t[threadIdx.y + i * 8][threadIdx.x] = (n < Cin) ? in[(size_t)k * Cin + n] : 0.f;
    }
    __syncthreads();
#pragma unroll
    for (int i = 0; i < 4; ++i) {
        int n = n0 + threadIdx.y + i * 8;
        int k = k0 + threadIdx.x;
        out[(size_t)n * R + k] = f2bu(t[threadIdx.x][threadIdx.y + i * 8]);
    }
}

// ---------------- bf16 MFMA GEMM (BT form) ----------------
// C[M,N] = alpha * A[M,K] * B[N,K]^T. A,B bf16 row-major, K-contiguous.
// 128x128 tile, BK=32, 4 waves, global_load_lds staging with slot-XOR swizzle
// (linear LDS dest + inverse-swizzled global source + swizzled frag read, rule #21).
// Requires M%128==0, K%32==0 (per split chunk), lda/ldb%8==0, bases 16B-aligned.
// STORE: 0 = bf16 C; 1 = bf16 C^T (C[(col)*ldc+row], packed 8B);
//        2 = fp32 C + bias + rowmap + col<N guard; 3 = fp32 atomicAdd (split-K).
// SPLITK: 1 -> blockIdx.z = batch (strides sA/sB/sC); >1 -> blockIdx.z = K-chunk.
template<int STORE, int SPLITK>
__global__ __launch_bounds__(256) void gemm_bt(
    const unsigned short* __restrict__ A, int lda, long long sA,
    const unsigned short* __restrict__ B, int ldb, long long sB,
    void* __restrict__ Cv, int ldc, long long sC,
    int M, int N, int K, float alpha,
    const float* __restrict__ bias, const int* __restrict__ rowmap)
{
    __shared__ unsigned short As[4096];  // 128 rows x 32 k (8 KB), slot-swizzled
    __shared__ unsigned short Bs[4096];
    const int tid = threadIdx.x;
    const int w = tid >> 6, l = tid & 63;
    const int m0 = blockIdx.x * 128, n0 = blockIdx.y * 128;

    int kbeg = 0, kend = K;
    if (SPLITK > 1) {
        int kc = K / SPLITK;
        kbeg = blockIdx.z * kc; kend = kbeg + kc;
    } else {
        A += (long long)blockIdx.z * sA;
        B += (long long)blockIdx.z * sB;
    }

    const int wr = (w >> 1) << 6, wc = (w & 1) << 6;
    const int lrow = l & 15, lk = l >> 4;

    // staging source mapping: LDS byte o = w*2048 + j*1024 + l*16
    // row r = o/64, lds slot s' = (o/16)&3, global slot = s' ^ ((r>>1)&3)
    const int o0 = (w << 11) + (l << 4);
    const int r0s = o0 >> 6;
    const int k0off = (((o0 >> 4) & 3) ^ ((r0s >> 1) & 3)) << 3;
    const int o1 = o0 + 1024;
    const int r1s = o1 >> 6;
    const int k1off = (((o1 >> 4) & 3) ^ ((r1s >> 1) & 3)) << 3;

    f32x4 acc[4][4];
#pragma unroll
    for (int mi = 0; mi < 4; ++mi)
#pragma unroll
        for (int ni = 0; ni < 4; ++ni)
            acc[mi][ni] = (f32x4){0.f, 0.f, 0.f, 0.f};

    const int rdslot = (lk ^ ((lrow >> 1) & 3)) << 4;  // frag-read swizzled slot byte

    for (int kt = kbeg; kt < kend; kt += 32) {
        gload16(A + (size_t)(m0 + r0s) * lda + kt + k0off, (char*)As + (w << 11));
        gload16(A + (size_t)(m0 + r1s) * lda + kt + k1off, (char*)As + (w << 11) + 1024);
        gload16(B + (size_t)(n0 + r0s) * ldb + kt + k0off, (char*)Bs + (w << 11));
        gload16(B + (size_t)(n0 + r1s) * ldb + kt + k1off, (char*)Bs + (w << 11) + 1024);
        __syncthreads();

        bf16x8 af[4], bfr[4];
#pragma unroll
        for (int mi = 0; mi < 4; ++mi) {
            int ra = wr + (mi << 4) + lrow;
            af[mi] = *reinterpret_cast<const bf16x8*>((const char*)As + (ra << 6) + rdslot);
        }
#pragma unroll
        for (int ni = 0; ni < 4; ++ni) {
            int rb = wc + (ni << 4) + lrow;
            bfr[ni] = *reinterpret_cast<const bf16x8*>((const char*)Bs + (rb << 6) + rdslot);
        }
#pragma unroll
        for (int mi = 0; mi < 4; ++mi)
#pragma unroll
            for (int ni = 0; ni < 4; ++ni)
                acc[mi][ni] = __builtin_amdgcn_mfma_f32_16x16x32_bf16(
                    af[mi], bfr[ni], acc[mi][ni], 0, 0, 0);
        __syncthreads();
    }

    // C/D layout: col = lane&15, row = (lane>>4)*4 + reg
    const long long czoff = (SPLITK > 1) ? 0 : (long long)blockIdx.z * sC;

    if (STORE == 0) {
        unsigned short* C = (unsigned short*)Cv + czoff;
#pragma unroll
        for (int mi = 0; mi < 4; ++mi) {
            int r = m0 + wr + (mi << 4) + (lk << 2);
#pragma unroll
            for (int ni = 0; ni < 4; ++ni) {
                int c = n0 + wc + (ni << 4) + lrow;
#pragma unroll
                for (int q = 0; q < 4; ++q)
                    C[(size_t)(r + q) * ldc + c] = f2bu(acc[mi][ni][q] * alpha);
            }
        }
    } else if (STORE == 1) {
        unsigned short* C = (unsigned short*)Cv + czoff;
#pragma unroll
        for (int ni = 0; ni < 4; ++ni) {
            int c = n0 + wc + (ni << 4) + lrow;
#pragma unroll
            for (int mi = 0; mi < 4; ++mi) {
                int r = m0 + wr + (mi << 4) + (lk << 2);
                ushort4 u;
                u.x = f2bu(acc[mi][ni][0] * alpha);
                u.y = f2bu(acc[mi][ni][1] * alpha);
                u.z = f2bu(acc[mi][ni][2] * alpha);
                u.w = f2bu(acc[mi][ni][3] * alpha);
                *reinterpret_cast<ushort4*>(&C[(size_t)c * ldc + r]) = u;
            }
        }
    } else if (STORE == 2) {
        float* C = (float*)Cv;
#pragma unroll
        for (int mi = 0; mi < 4; ++mi) {
            int r = m0 + wr + (mi << 4) + (lk << 2);
#pragma unroll
            for (int q = 0; q < 4; ++q) {
                int rm = rowmap[r + q];
                if (rm < 0) continue;
#pragma unroll
                for (int ni = 0; ni < 4; ++ni) {
                    int c = n0 + wc + (ni << 4) + lrow;
                    if (c < N) C[(size_t)rm * ldc + c] = acc[mi][ni][q] * alpha + bias[c];
                }
            }
        }
    } else {
        float* C = (float*)Cv + czoff;
#pragma unroll
        for (int mi = 0; mi < 4; ++mi) {
            int r = m0 + wr + (mi << 4) + (lk << 2);
#pragma unroll
            for (int ni = 0; ni < 4; ++ni) {
                int c = n0 + wc + (ni << 4) + lrow;
#pragma unroll
                for (int q = 0; q < 4; ++q)
                    atomicAdd(&C[(size_t)(r + q) * ldc + c], acc[mi][ni][q] * alpha);
            }
        }
    }
}

// ---------------- masked row softmax on bf16 (row length = CNT*256) ----------------
template<int CNT>
__global__ __launch_bounds__(256) void softmax_bf16(
    unsigned short* __restrict__ S, const unsigned char* __restrict__ mask)
{
    __shared__ float red[4];
    const int b = blockIdx.y;
    unsigned short* p = S + ((long long)b * TT + blockIdx.x) * (CNT * 256);
    const unsigned char* mk = mask + (long long)b * (CNT * 256);
    const int tid = threadIdx.x;

    float v[CNT];
    float mx = -FLT_MAX;
#pragma unroll
    for (int c = 0; c < CNT; ++c) {
        int j = (c << 8) + tid;
        float s = bu2f(p[j]);
        if (mk[j]) s = -FLT_MAX;
        v[c] = s;
        mx = fmaxf(mx, s);
    }
#pragma unroll
    for (int off = 32; off > 0; off >>= 1) mx = fmaxf(mx, __shfl_down(mx, off));
    if ((tid & 63) == 0) red[tid >> 6] = mx;
    __syncthreads();
    mx = fmaxf(fmaxf(red[0], red[1]), fmaxf(red[2], red[3]));
    __syncthreads();

    float sum = 0.f;
#pragma unroll
    for (int c = 0; c < CNT; ++c) {
        float e = expf(v[c] - mx);
        v[c] = e;
        sum += e;
    }
#pragma unroll
    for (int off = 32; off > 0; off >>= 1) sum += __shfl_down(sum, off);
    if ((tid & 63) == 0) red[tid >> 6] = sum;
    __syncthreads();
    sum = red[0] + red[1] + red[2] + red[3];
    float inv = 1.f / sum;
#pragma unroll
    for (int c = 0; c < CNT; ++c) p[(c << 8) + tid] = f2bu(v[c] * inv);
}

// ---------------- residual + LayerNorm (in place on x, emits bf16 copy) ----------------
__global__ __launch_bounds__(256) void ln_kernel(
    float* __restrict__ x, const float* __restrict__ a,
    const float* __restrict__ abias,
    const float* __restrict__ g, const float* __restrict__ be,
    unsigned short* __restrict__ xb)
{
    __shared__ float red[4];
    const long long r = blockIdx.x;
    const int d = threadIdx.x;
    const long long idx = r * DD + d;
    float v = x[idx] + a[idx];
    if (abias) v += abias[d];

    float s = v;
#pragma unroll
    for (int off = 32; off > 0; off >>= 1) s += __shfl_down(s, off);
    if ((d & 63) == 0) red[d >> 6] = s;
    __syncthreads();
    float mean = (red[0] + red[1] + red[2] + red[3]) * (1.f / DD);
    __syncthreads();

    float df = v - mean;
    float s2 = df * df;
#pragma unroll
    for (int off = 32; off > 0; off >>= 1) s2 += __shfl_down(s2, off);
    if ((d & 63) == 0) red[d >> 6] = s2;
    __syncthreads();
    float var = (red[0] + red[1] + red[2] + red[3]) * (1.f / DD);

    float o = df / sqrtf(var + 1e-5f) * g[d] + be[d];
    x[idx] = o;
    xb[idx] = f2bu(o);
}

// ---------------- small fp32 SGEMM for FFN: 64x64 tile, BK=16, 4x4/thread ----------------
// mode: 0 = store, 2 = store+bias+exact-GELU
__global__ __launch_bounds__(256) void sgemm_small(
    const float* __restrict__ A, int lda,
    const float* __restrict__ Bm, int ldb,
    float* __restrict__ C, int ldc,
    int M, int N, int K, int mode, const float* __restrict__ bias)
{
    __shared__ float As[16][64];
    __shared__ float Bs[16][64];
    const int tid = threadIdx.x;
    const int tx = tid & 15, ty = tid >> 4;
    const int m0 = blockIdx.x * 64;
    const int n0 = blockIdx.y * 64;
    const int ar = tid >> 2, ak = (tid & 3) * 4;
    const int bk = tid >> 4, bn = (tid & 15) * 4;

    float acc[4][4];
#pragma unroll
    for (int i = 0; i < 4; ++i)
#pragma unroll
        for (int j = 0; j < 4; ++j) acc[i][j] = 0.f;

    for (int kt = 0; kt < K; kt += 16) {
        {
            const float4 va = *reinterpret_cast<const float4*>(
                A + (long long)(m0 + ar) * lda + (kt + ak));
            As[ak + 0][ar] = va.x; As[ak + 1][ar] = va.y;
            As[ak + 2][ar] = va.z; As[ak + 3][ar] = va.w;
        }
        {
            const float4 vb = *reinterpret_cast<const float4*>(
                Bm + (long long)(kt + bk) * ldb + (n0 + bn));
            *reinterpret_cast<float4*>(&Bs[bk][bn]) = vb;
        }
        __syncthreads();
#pragma unroll
        for (int k = 0; k < 16; ++k) {
            float a[4], b[4];
#pragma unroll
            for (int i = 0; i < 4; ++i) a[i] = As[k][ty + i * 16];
#pragma unroll
            for (int j = 0; j < 4; ++j) b[j] = Bs[k][tx + j * 16];
#pragma unroll
            for (int i = 0; i < 4; ++i)
#pragma unroll
                for (int j = 0; j < 4; ++j)
                    acc[i][j] = fmaf(a[i], b[j], acc[i][j]);
        }
        __syncthreads();
    }

#pragma unroll
    for (int i = 0; i < 4; ++i) {
        int r = m0 + ty + i * 16;
        float* crow = C + (long long)r * ldc;
#pragma unroll
        for (int j = 0; j < 4; ++j) {
            int n = n0 + tx + j * 16;
            float v = acc[i][j];
            if (mode >= 1) v += bias[n];
            if (mode == 2) v = 0.5f * v * (1.f + erff(v * 0.70710678118f));
            crow[n] = v;
        }
    }
}

// ---------------- launch ----------------
extern "C" void kernel_launch(void* const* d_in, const int* in_sizes, int n_in,
                              void* d_out, int out_size, void* d_ws, size_t ws_size,
                              hipStream_t stream)
{
    const int*   src_ids = (const int*)d_in[0];
    const int*   t1      = (const int*)d_in[1];
    const int*   t2      = (const int*)d_in[2];
    const float* enc  = (const float*)d_in[4];
    const float* emb  = (const float*)d_in[5];
    const float* Wq_s = (const float*)d_in[6];
    const float* Wk_s = (const float*)d_in[7];
    const float* Wv_s = (const float*)d_in[8];
    const float* Wo_s = (const float*)d_in[9];
    const float* bo_s = (const float*)d_in[10];
    const float* Wq_c = (const float*)d_in[11];
    const float* Wk_c = (const float*)d_in[12];
    const float* Wv_c = (const float*)d_in[13];
    const float* Wo_c = (const float*)d_in[14];
    const float* bo_c = (const float*)d_in[15];
    const float* W1   = (const float*)d_in[16];
    const float* b1   = (const float*)d_in[17];
    const float* W2   = (const float*)d_in[18];
    const float* b2   = (const float*)d_in[19];
    const float* g1   = (const float*)d_in[20];
    const float* g2   = (const float*)d_in[21];
    const float* g3   = (const float*)d_in[22];
    const float* be1  = (const float*)d_in[23];
    const float* be2  = (const float*)d_in[24];
    const float* be3  = (const float*)d_in[25];
    const float* Wfc  = (const float*)d_in[26];
    const float* bfc  = (const float*)d_in[27];

    // ---------------- workspace layout (~114 MB, under proven ws_size >= 126 MB) ----
    char* p = (char*)d_ws;
    float* x    = (float*)p;           p += (size_t)ROWS * DD * 4;
    float* aout = (float*)p;           p += (size_t)ROWS * DD * 4;
    unsigned short* xb   = (unsigned short*)p; p += (size_t)ROWS * DD * 2;
    unsigned short* encb = (unsigned short*)p; p += (size_t)SROWS * DD * 2;
    unsigned short* WqTs = (unsigned short*)p; p += (size_t)INNER_ * DD * 2;
    unsigned short* WkTs = (unsigned short*)p; p += (size_t)INNER_ * DD * 2;
    unsigned short* WvTs = (unsigned short*)p; p += (size_t)INNER_ * DD * 2;
    unsigned short* WqTc = (unsigned short*)p; p += (size_t)INNER_ * DD * 2;
    unsigned short* WkTc = (unsigned short*)p; p += (size_t)INNER_ * DD * 2;
    unsigned short* WvTc = (unsigned short*)p; p += (size_t)INNER_ * DD * 2;
    unsigned short* WoTs = (unsigned short*)p; p += (size_t)DD * INNER_ * 2;
    unsigned short* WoTc = (unsigned short*)p; p += (size_t)DD * INNER_ * 2;
    unsigned short* WfcT = (unsigned short*)p; p += (size_t)VPAD * DD * 2;
    unsigned short* Qh   = (unsigned short*)p; p += (size_t)ROWS * DHD * 2;  // 12.6 MB
    unsigned short* Kh   = (unsigned short*)p; p += (size_t)ROWS * DHD * 2;
    unsigned char* tgtpad = (unsigned char*)p; p += ROWS;
    unsigned char* srcpad = (unsigned char*)p; p += SROWS;
    p = (char*)(((size_t)p + 15) & ~(size_t)15);
    int* rowmap = (int*)p;             p += (size_t)ROWS * 4;

    // Large transients live in d_out (312 MB; all dead before the logits GEMM
    // overwrites the entire output region):
    //   Oall [3072,16384] bf16 = 100.66 MB, simb 9.44 MB, Vt 12.58 MB
    char* q = (char*)d_out;
    unsigned short* Oall = (unsigned short*)q;  q += (size_t)ROWS * INNER_ * 2;
    unsigned short* simb = (unsigned short*)q;  q += (size_t)BB * TT * TT * 2;
    unsigned short* Vt   = (unsigned short*)q;  q += (size_t)DHD * ROWS * 2;

    // ---------------- prep ----------------
    embed_kernel<<<dim3(TT, BB), 256, 0, stream>>>(t1, t2, emb, x, xb, tgtpad);
    srcmask_kernel<<<dim3(SROWS / 256), 256, 0, stream>>>(src_ids, srcpad);
    rowmap_kernel<<<dim3(ROWS / 256 + 1), 256, 0, stream>>>(rowmap);
    conv_bf16<<<dim3((SROWS * DD) / 256), 256, 0, stream>>>(enc, encb, SROWS * DD);

    dim3 tcb(32, 8);
    transpose_conv<<<dim3(8, 512), tcb, 0, stream>>>(Wq_s, WqTs, DD, INNER_, INNER_);
    transpose_conv<<<dim3(8, 512), tcb, 0, stream>>>(Wk_s, WkTs, DD, INNER_, INNER_);
    transpose_conv<<<dim3(8, 512), tcb, 0, stream>>>(Wv_s, WvTs, DD, INNER_, INNER_);
    transpose_conv<<<dim3(8, 512), tcb, 0, stream>>>(Wq_c, WqTc, DD, INNER_, INNER_);
    transpose_conv<<<dim3(8, 512), tcb, 0, stream>>>(Wk_c, WkTc, DD, INNER_, INNER_);
    transpose_conv<<<dim3(8, 512), tcb, 0, stream>>>(Wv_c, WvTc, DD, INNER_, INNER_);
    transpose_conv<<<dim3(512, 8), tcb, 0, stream>>>(Wo_s, WoTs, INNER_, DD, DD);
    transpose_conv<<<dim3(512, 8), tcb, 0, stream>>>(Wo_c, WoTc, INNER_, DD, DD);
    transpose_conv<<<dim3(8, VPAD / 32), tcb, 0, stream>>>(Wfc, WfcT, DD, VV, VPAD);

    const float scale = 0.022097086912079608f;  // DH^-0.5
    const long long QS = (long long)TT * DHD;   // per-batch stride in Qh/Kh

    // ---------------- self attention ----------------
    hipMemsetAsync(aout, 0, (size_t)ROWS * DD * sizeof(float), stream);
    for (int h = 0; h < HH; ++h) {
        const size_t wof = (size_t)h * DHD * DD;
        gemm_bt<0, 1><<<dim3(24, 16, 1), 256, 0, stream>>>(
            xb, DD, 0, WqTs + wof, DD, 0, Qh, DHD, 0,
            ROWS, DHD, DD, 1.f, nullptr, nullptr);
        gemm_bt<0, 1><<<dim3(24, 16, 1), 256, 0, stream>>>(
            xb, DD, 0, WkTs + wof, DD, 0, Kh, DHD, 0,
            ROWS, DHD, DD, 1.f, nullptr, nullptr);
        gemm_bt<1, 1><<<dim3(24, 16, 1), 256, 0, stream>>>(
            xb, DD, 0, WvTs + wof, DD, 0, Vt, ROWS, 0,
            ROWS, DHD, DD, 1.f, nullptr, nullptr);
        gemm_bt<0, 1><<<dim3(12, 12, BB), 256, 0, stream>>>(
            Qh, DHD, QS, Kh, DHD, QS, simb, TT, (long long)TT * TT,
            TT, TT, DHD, scale, nullptr, nullptr);
        softmax_bf16<6><<<dim3(TT, BB), 256, 0, stream>>>(simb, tgtpad);
        gemm_bt<0, 1><<<dim3(12, 16, BB), 256, 0, stream>>>(
            simb, TT, (long long)TT * TT, Vt, ROWS, TT,
            Oall + (size_t)h * DHD, INNER_, (long long)TT * INNER_,
            TT, DHD, TT, 1.f, nullptr, nullptr);
    }
    gemm_bt<3, 8><<<dim3(24, 2, 8), 256, 0, stream>>>(
        Oall, INNER_, 0, WoTs, INNER_, 0, aout, DD, 0,
        ROWS, DD, INNER_, 1.f, nullptr, nullptr);
    ln_kernel<<<dim3(ROWS), 256, 0, stream>>>(x, aout, bo_s, g1, be1, xb);

    // ---------------- cross attention ----------------
    hipMemsetAsync(aout, 0, (size_t)ROWS * DD * sizeof(float), stream);
    for (int h = 0; h < HH; ++h) {
        const size_t wof = (size_t)h * DHD * DD;
        gemm_bt<0, 1><<<dim3(24, 16, 1), 256, 0, stream>>>(
            xb, DD, 0, WqTc + wof, DD, 0, Qh, DHD, 0,
            ROWS, DHD, DD, 1.f, nullptr, nullptr);
        gemm_bt<0, 1><<<dim3(16, 16, 1), 256, 0, stream>>>(
            encb, DD, 0, WkTc + wof, DD, 0, Kh, DHD, 0,
            SROWS, DHD, DD, 1.f, nullptr, nullptr);
        gemm_bt<1, 1><<<dim3(16, 16, 1), 256, 0, stream>>>(
            encb, DD, 0, WvTc + wof, DD, 0, Vt, SROWS, 0,
            SROWS, DHD, DD, 1.f, nullptr, nullptr);
        gemm_bt<0, 1><<<dim3(12, 8, BB), 256, 0, stream>>>(
            Qh, DHD, QS, Kh, DHD, (long long)SS * DHD,
            simb, SS, (long long)TT * SS,
            TT, SS, DHD, scale, nullptr, nullptr);
        softmax_bf16<4><<<dim3(TT, BB), 256, 0, stream>>>(simb, srcpad);
        gemm_bt<0, 1><<<dim3(12, 16, BB), 256, 0, stream>>>(
            simb, SS, (long long)TT * SS, Vt, SROWS, SS,
            Oall + (size_t)h * DHD, INNER_, (long long)TT * INNER_,
            TT, DHD, SS, 1.f, nullptr, nullptr);
    }
    gemm_bt<3, 8><<<dim3(24, 2, 8), 256, 0, stream>>>(
        Oall, INNER_, 0, WoTc, INNER_, 0, aout, DD, 0,
        ROWS, DD, INNER_, 1.f, nullptr, nullptr);
    ln_kernel<<<dim3(ROWS), 256, 0, stream>>>(x, aout, bo_c, g2, be2, xb);

    // ---------------- FFN (D->D->D, exact GELU), fp32 ----------------
    float* h1 = (float*)Qh;  // reuse
    sgemm_small<<<dim3(ROWS / 64, DD / 64, 1), 256, 0, stream>>>(
        x, DD, W1, DD, h1, DD, ROWS, DD, DD, 2, b1);
    sgemm_small<<<dim3(ROWS / 64, DD / 64, 1), 256, 0, stream>>>(
        h1, DD, W2, DD, aout, DD, ROWS, DD, DD, 0, nullptr);
    ln_kernel<<<dim3(ROWS), 256, 0, stream>>>(x, aout, b2, g3, be3, xb);

    // ---------------- logits (bf16 MFMA, rowmap drops t==0 rows) ----------------
    gemm_bt<2, 1><<<dim3(24, VPAD / 128, 1), 256, 0, stream>>>(
        xb, DD, 0, WfcT, DD, 0, d_out, VV, 0,
        ROWS, VV, DD, 1.f, bfc, rowmap);

    // ---------------- second output: x[:,0,:] ----------------
    copycls_kernel<<<dim3(BB), 256, 0, stream>>>(
        x, (float*)d_out + (long long)BB * (TT - 1) * VV);
}

// Round 5
// 1617.500 us; speedup vs baseline: 10.5965x; 1.5281x over previous
//
#include <hip/hip_runtime.h>
#include <hip/hip_bf16.h>
#include <float.h>
#include <math.h>

// ---------------- problem constants ----------------
#define BB 2
#define SS 1024
#define LL 767
#define TT 1536          // 2*(LL+1)
#define DD 256
#define HH 8
#define DHD 2048
#define INNER_ 16384
#define VV 25426
#define VPAD 25472       // VV padded to multiple of 128
#define CLS_TOK 25426
#define MASK_TOKEN 25428
#define ROWS (BB*TT)     // 3072
#define SROWS (BB*SS)    // 2048
#define GN 8192          // 4 heads * DHD = group width

typedef __attribute__((ext_vector_type(8))) __bf16 bf16x8;
typedef __attribute__((ext_vector_type(4))) float f32x4;

__device__ __forceinline__ unsigned short f2bu(float f) {
    union { float f; unsigned u; } v; v.f = f;
    unsigned r = v.u + 0x7fff + ((v.u >> 16) & 1);
    return (unsigned short)(r >> 16);
}
__device__ __forceinline__ float bu2f(unsigned short u) {
    union { unsigned u; float f; } v; v.u = ((unsigned)u) << 16;
    return v.f;
}

__device__ __forceinline__ void gload16(const void* g, void* l) {
    __builtin_amdgcn_global_load_lds(
        (const __attribute__((address_space(1))) void*)g,
        (__attribute__((address_space(3))) void*)l, 16, 0, 0);
}

// ---------------- small helper kernels ----------------

__global__ __launch_bounds__(256) void embed_kernel(
    const int* __restrict__ t1, const int* __restrict__ t2,
    const float* __restrict__ emb, float* __restrict__ x,
    unsigned short* __restrict__ xb, unsigned char* __restrict__ tgt_pad)
{
    int t = blockIdx.x, b = blockIdx.y, d = threadIdx.x;
    int raw;
    if (t == 0)            raw = CLS_TOK;
    else if (t <= LL)      raw = t1[b * LL + (t - 1)];
    else if (t == LL + 1)  raw = CLS_TOK;
    else                   raw = t2[b * LL + (t - LL - 2)];
    int id = (raw == 0 || raw == MASK_TOKEN) ? MASK_TOKEN : raw;
    int i = d >> 1;
    float ang = (float)t * expf(-0.03597789208f * (float)(2 * i));
    float pe = (d & 1) ? cosf(ang) : sinf(ang);
    float val = 2.f * emb[(long long)id * DD + d] + pe;
    long long idx = ((long long)(b * TT + t)) * DD + d;
    x[idx] = val;
    xb[idx] = f2bu(val);
    if (d == 0) tgt_pad[b * TT + t] = (raw == 0) ? 1 : 0;
}

__global__ __launch_bounds__(256) void srcmask_kernel(
    const int* __restrict__ src, unsigned char* __restrict__ m)
{
    int i = blockIdx.x * 256 + threadIdx.x;
    if (i < SROWS) m[i] = (src[i] == 0) ? 1 : 0;
}

__global__ __launch_bounds__(256) void rowmap_kernel(int* __restrict__ rm)
{
    int r = blockIdx.x * 256 + threadIdx.x;
    if (r >= ROWS) return;
    int b = r / TT, t = r % TT;
    rm[r] = (t == 0) ? -1 : (b * (TT - 1) + t - 1);
}

__global__ __launch_bounds__(256) void copycls_kernel(
    const float* __restrict__ x, float* __restrict__ out2)
{
    int b = blockIdx.x, d = threadIdx.x;
    out2[b * DD + d] = x[(long long)b * TT * DD + d];
}

__global__ __launch_bounds__(256) void conv_bf16(
    const float* __restrict__ in, unsigned short* __restrict__ out, int n)
{
    int i = blockIdx.x * 256 + threadIdx.x;
    if (i < n) out[i] = f2bu(in[i]);
}

// transpose + convert: out[n][k] = bf16(in[k][n]); in [R][Cin] f32, out [Nout][R] bf16.
__global__ __launch_bounds__(256) void transpose_conv(
    const float* __restrict__ in, unsigned short* __restrict__ out,
    int R, int Cin, int Nout)
{
    __shared__ float t[32][33];
    int k0 = blockIdx.x * 32, n0 = blockIdx.y * 32;
#pragma unroll
    for (int i = 0; i < 4; ++i) {
        int k = k0 + threadIdx.y + i * 8;
        int n = n0 + threadIdx.x;
        t[threadIdx.y + i * 8][threadIdx.x] = (n < Cin) ? in[(size_t)k * Cin + n] : 0.f;
    }
    __syncthreads();
#pragma unroll
    for (int i = 0; i < 4; ++i) {
        int n = n0 + threadIdx.y + i * 8;
        int k = k0 + threadIdx.x;
        out[(size_t)n * R + k] = f2bu(t[threadIdx.x][threadIdx.y + i * 8]);
    }
}

// ---------------- bf16 MFMA GEMM (BT form, z-batched) ----------------
// C[M,N] = alpha * A[M,K] * B[N,K]^T. A,B bf16 row-major, K-contiguous.
// 128x128 tile, BK=32, 4 waves, global_load_lds staging with slot-XOR swizzle.
// z decode (SPLITK==1): zb = z>>zs, zh = z - (zb<<zs); operand offsets
//   A += zb*sAb + zh*sAh  (same for B, C). SPLITK>1: z = K-chunk index.
// STORE: 0 = bf16 C; 1 = bf16 C^T (packed 8B); 2 = fp32 C + bias + rowmap;
//        3 = fp32 atomicAdd (split-K).
template<int STORE, int SPLITK>
__global__ __launch_bounds__(256) void gemm_bt(
    const unsigned short* __restrict__ A, int lda,
    const unsigned short* __restrict__ B, int ldb,
    void* __restrict__ Cv, int ldc,
    int M, int N, int K, float alpha, int zs,
    long long sAb, long long sAh, long long sBb, long long sBh,
    long long sCb, long long sCh,
    const float* __restrict__ bias, const int* __restrict__ rowmap)
{
    __shared__ unsigned short As[4096];  // 128 rows x 32 k (8 KB), slot-swizzled
    __shared__ unsigned short Bs[4096];
    const int tid = threadIdx.x;
    const int w = tid >> 6, l = tid & 63;
    const int m0 = blockIdx.x * 128, n0 = blockIdx.y * 128;

    int kbeg = 0, kend = K;
    long long czoff = 0;
    if (SPLITK > 1) {
        int kc = K / SPLITK;
        kbeg = blockIdx.z * kc; kend = kbeg + kc;
    } else {
        int zb = blockIdx.z >> zs;
        int zh = blockIdx.z - (zb << zs);
        A += zb * sAb + zh * sAh;
        B += zb * sBb + zh * sBh;
        czoff = zb * sCb + zh * sCh;
    }

    const int wr = (w >> 1) << 6, wc = (w & 1) << 6;
    const int lrow = l & 15, lk = l >> 4;

    // staging source mapping: LDS byte o = w*2048 + j*1024 + l*16
    // row r = o/64, lds slot s' = (o/16)&3, global slot = s' ^ ((r>>1)&3)
    const int o0 = (w << 11) + (l << 4);
    const int r0s = o0 >> 6;
    const int k0off = (((o0 >> 4) & 3) ^ ((r0s >> 1) & 3)) << 3;
    const int o1 = o0 + 1024;
    const int r1s = o1 >> 6;
    const int k1off = (((o1 >> 4) & 3) ^ ((r1s >> 1) & 3)) << 3;

    f32x4 acc[4][4];
#pragma unroll
    for (int mi = 0; mi < 4; ++mi)
#pragma unroll
        for (int ni = 0; ni < 4; ++ni)
            acc[mi][ni] = (f32x4){0.f, 0.f, 0.f, 0.f};

    const int rdslot = (lk ^ ((lrow >> 1) & 3)) << 4;  // frag-read swizzled slot byte

    for (int kt = kbeg; kt < kend; kt += 32) {
        gload16(A + (size_t)(m0 + r0s) * lda + kt + k0off, (char*)As + (w << 11));
        gload16(A + (size_t)(m0 + r1s) * lda + kt + k1off, (char*)As + (w << 11) + 1024);
        gload16(B + (size_t)(n0 + r0s) * ldb + kt + k0off, (char*)Bs + (w << 11));
        gload16(B + (size_t)(n0 + r1s) * ldb + kt + k1off, (char*)Bs + (w << 11) + 1024);
        __syncthreads();

        bf16x8 af[4], bfr[4];
#pragma unroll
        for (int mi = 0; mi < 4; ++mi) {
            int ra = wr + (mi << 4) + lrow;
            af[mi] = *reinterpret_cast<const bf16x8*>((const char*)As + (ra << 6) + rdslot);
        }
#pragma unroll
        for (int ni = 0; ni < 4; ++ni) {
            int rb = wc + (ni << 4) + lrow;
            bfr[ni] = *reinterpret_cast<const bf16x8*>((const char*)Bs + (rb << 6) + rdslot);
        }
#pragma unroll
        for (int mi = 0; mi < 4; ++mi)
#pragma unroll
            for (int ni = 0; ni < 4; ++ni)
                acc[mi][ni] = __builtin_amdgcn_mfma_f32_16x16x32_bf16(
                    af[mi], bfr[ni], acc[mi][ni], 0, 0, 0);
        __syncthreads();
    }

    // C/D layout: col = lane&15, row = (lane>>4)*4 + reg
    if (STORE == 0) {
        unsigned short* C = (unsigned short*)Cv + czoff;
#pragma unroll
        for (int mi = 0; mi < 4; ++mi) {
            int r = m0 + wr + (mi << 4) + (lk << 2);
#pragma unroll
            for (int ni = 0; ni < 4; ++ni) {
                int c = n0 + wc + (ni << 4) + lrow;
#pragma unroll
                for (int q = 0; q < 4; ++q)
                    C[(size_t)(r + q) * ldc + c] = f2bu(acc[mi][ni][q] * alpha);
            }
        }
    } else if (STORE == 1) {
        unsigned short* C = (unsigned short*)Cv + czoff;
#pragma unroll
        for (int ni = 0; ni < 4; ++ni) {
            int c = n0 + wc + (ni << 4) + lrow;
#pragma unroll
            for (int mi = 0; mi < 4; ++mi) {
                int r = m0 + wr + (mi << 4) + (lk << 2);
                ushort4 u;
                u.x = f2bu(acc[mi][ni][0] * alpha);
                u.y = f2bu(acc[mi][ni][1] * alpha);
                u.z = f2bu(acc[mi][ni][2] * alpha);
                u.w = f2bu(acc[mi][ni][3] * alpha);
                *reinterpret_cast<ushort4*>(&C[(size_t)c * ldc + r]) = u;
            }
        }
    } else if (STORE == 2) {
        float* C = (float*)Cv;
#pragma unroll
        for (int mi = 0; mi < 4; ++mi) {
            int r = m0 + wr + (mi << 4) + (lk << 2);
#pragma unroll
            for (int q = 0; q < 4; ++q) {
                int rm = rowmap[r + q];
                if (rm < 0) continue;
#pragma unroll
                for (int ni = 0; ni < 4; ++ni) {
                    int c = n0 + wc + (ni << 4) + lrow;
                    if (c < N) C[(size_t)rm * ldc + c] = acc[mi][ni][q] * alpha + bias[c];
                }
            }
        }
    } else {
        float* C = (float*)Cv;
#pragma unroll
        for (int mi = 0; mi < 4; ++mi) {
            int r = m0 + wr + (mi << 4) + (lk << 2);
#pragma unroll
            for (int ni = 0; ni < 4; ++ni) {
                int c = n0 + wc + (ni << 4) + lrow;
#pragma unroll
                for (int q = 0; q < 4; ++q)
                    atomicAdd(&C[(size_t)(r + q) * ldc + c], acc[mi][ni][q] * alpha);
            }
        }
    }
}

// ---------------- masked row softmax on bf16, z-batched over (b,h) ----------------
// sim layout: [z][TT][CNT*256]; mask per batch b = z>>zs.
template<int CNT>
__global__ __launch_bounds__(256) void softmax_bf16(
    unsigned short* __restrict__ S, const unsigned char* __restrict__ mask, int zs)
{
    __shared__ float red[4];
    const int z = blockIdx.y;
    unsigned short* p = S + ((long long)z * TT + blockIdx.x) * (CNT * 256);
    const unsigned char* mk = mask + (long long)(z >> zs) * (CNT * 256);
    const int tid = threadIdx.x;

    float v[CNT];
    float mx = -FLT_MAX;
#pragma unroll
    for (int c = 0; c < CNT; ++c) {
        int j = (c << 8) + tid;
        float s = bu2f(p[j]);
        if (mk[j]) s = -FLT_MAX;
        v[c] = s;
        mx = fmaxf(mx, s);
    }
#pragma unroll
    for (int off = 32; off > 0; off >>= 1) mx = fmaxf(mx, __shfl_down(mx, off));
    if ((tid & 63) == 0) red[tid >> 6] = mx;
    __syncthreads();
    mx = fmaxf(fmaxf(red[0], red[1]), fmaxf(red[2], red[3]));
    __syncthreads();

    float sum = 0.f;
#pragma unroll
    for (int c = 0; c < CNT; ++c) {
        float e = expf(v[c] - mx);
        v[c] = e;
        sum += e;
    }
#pragma unroll
    for (int off = 32; off > 0; off >>= 1) sum += __shfl_down(sum, off);
    if ((tid & 63) == 0) red[tid >> 6] = sum;
    __syncthreads();
    sum = red[0] + red[1] + red[2] + red[3];
    float inv = 1.f / sum;
#pragma unroll
    for (int c = 0; c < CNT; ++c) p[(c << 8) + tid] = f2bu(v[c] * inv);
}

// ---------------- residual + LayerNorm (in place on x, emits bf16 copy) ----------------
__global__ __launch_bounds__(256) void ln_kernel(
    float* __restrict__ x, const float* __restrict__ a,
    const float* __restrict__ abias,
    const float* __restrict__ g, const float* __restrict__ be,
    unsigned short* __restrict__ xb)
{
    __shared__ float red[4];
    const long long r = blockIdx.x;
    const int d = threadIdx.x;
    const long long idx = r * DD + d;
    float v = x[idx] + a[idx];
    if (abias) v += abias[d];

    float s = v;
#pragma unroll
    for (int off = 32; off > 0; off >>= 1) s += __shfl_down(s, off);
    if ((d & 63) == 0) red[d >> 6] = s;
    __syncthreads();
    float mean = (red[0] + red[1] + red[2] + red[3]) * (1.f / DD);
    __syncthreads();

    float df = v - mean;
    float s2 = df * df;
#pragma unroll
    for (int off = 32; off > 0; off >>= 1) s2 += __shfl_down(s2, off);
    if ((d & 63) == 0) red[d >> 6] = s2;
    __syncthreads();
    float var = (red[0] + red[1] + red[2] + red[3]) * (1.f / DD);

    float o = df / sqrtf(var + 1e-5f) * g[d] + be[d];
    x[idx] = o;
    xb[idx] = f2bu(o);
}

// ---------------- small fp32 SGEMM for FFN: 64x64 tile, BK=16, 4x4/thread ----------------
__global__ __launch_bounds__(256) void sgemm_small(
    const float* __restrict__ A, int lda,
    const float* __restrict__ Bm, int ldb,
    float* __restrict__ C, int ldc,
    int M, int N, int K, int mode, const float* __restrict__ bias)
{
    __shared__ float As[16][64];
    __shared__ float Bs[16][64];
    const int tid = threadIdx.x;
    const int tx = tid & 15, ty = tid >> 4;
    const int m0 = blockIdx.x * 64;
    const int n0 = blockIdx.y * 64;
    const int ar = tid >> 2, ak = (tid & 3) * 4;
    const int bk = tid >> 4, bn = (tid & 15) * 4;

    float acc[4][4];
#pragma unroll
    for (int i = 0; i < 4; ++i)
#pragma unroll
        for (int j = 0; j < 4; ++j) acc[i][j] = 0.f;

    for (int kt = 0; kt < K; kt += 16) {
        {
            const float4 va = *reinterpret_cast<const float4*>(
                A + (long long)(m0 + ar) * lda + (kt + ak));
            As[ak + 0][ar] = va.x; As[ak + 1][ar] = va.y;
            As[ak + 2][ar] = va.z; As[ak + 3][ar] = va.w;
        }
        {
            const float4 vb = *reinterpret_cast<const float4*>(
                Bm + (long long)(kt + bk) * ldb + (n0 + bn));
            *reinterpret_cast<float4*>(&Bs[bk][bn]) = vb;
        }
        __syncthreads();
#pragma unroll
        for (int k = 0; k < 16; ++k) {
            float a[4], b[4];
#pragma unroll
            for (int i = 0; i < 4; ++i) a[i] = As[k][ty + i * 16];
#pragma unroll
            for (int j = 0; j < 4; ++j) b[j] = Bs[k][tx + j * 16];
#pragma unroll
            for (int i = 0; i < 4; ++i)
#pragma unroll
                for (int j = 0; j < 4; ++j)
                    acc[i][j] = fmaf(a[i], b[j], acc[i][j]);
        }
        __syncthreads();
    }

#pragma unroll
    for (int i = 0; i < 4; ++i) {
        int r = m0 + ty + i * 16;
        float* crow = C + (long long)r * ldc;
#pragma unroll
        for (int j = 0; j < 4; ++j) {
            int n = n0 + tx + j * 16;
            float v = acc[i][j];
            if (mode >= 1) v += bias[n];
            if (mode == 2) v = 0.5f * v * (1.f + erff(v * 0.70710678118f));
            crow[n] = v;
        }
    }
}

// ---------------- launch ----------------
extern "C" void kernel_launch(void* const* d_in, const int* in_sizes, int n_in,
                              void* d_out, int out_size, void* d_ws, size_t ws_size,
                              hipStream_t stream)
{
    const int*   src_ids = (const int*)d_in[0];
    const int*   t1      = (const int*)d_in[1];
    const int*   t2      = (const int*)d_in[2];
    const float* enc  = (const float*)d_in[4];
    const float* emb  = (const float*)d_in[5];
    const float* Wq_s = (const float*)d_in[6];
    const float* Wk_s = (const float*)d_in[7];
    const float* Wv_s = (const float*)d_in[8];
    const float* Wo_s = (const float*)d_in[9];
    const float* bo_s = (const float*)d_in[10];
    const float* Wq_c = (const float*)d_in[11];
    const float* Wk_c = (const float*)d_in[12];
    const float* Wv_c = (const float*)d_in[13];
    const float* Wo_c = (const float*)d_in[14];
    const float* bo_c = (const float*)d_in[15];
    const float* W1   = (const float*)d_in[16];
    const float* b1   = (const float*)d_in[17];
    const float* W2   = (const float*)d_in[18];
    const float* b2   = (const float*)d_in[19];
    const float* g1   = (const float*)d_in[20];
    const float* g2v  = (const float*)d_in[21];
    const float* g3   = (const float*)d_in[22];
    const float* be1  = (const float*)d_in[23];
    const float* be2  = (const float*)d_in[24];
    const float* be3  = (const float*)d_in[25];
    const float* Wfc  = (const float*)d_in[26];
    const float* bfc  = (const float*)d_in[27];

    // ---------------- d_ws layout (~89 MB) ----------------
    char* p = (char*)d_ws;
    float* x    = (float*)p;           p += (size_t)ROWS * DD * 4;
    float* aout = (float*)p;           p += (size_t)ROWS * DD * 4;
    unsigned short* xb   = (unsigned short*)p; p += (size_t)ROWS * DD * 2;
    unsigned short* encb = (unsigned short*)p; p += (size_t)SROWS * DD * 2;
    unsigned short* WqTs = (unsigned short*)p; p += (size_t)INNER_ * DD * 2;
    unsigned short* WkTs = (unsigned short*)p; p += (size_t)INNER_ * DD * 2;
    unsigned short* WvTs = (unsigned short*)p; p += (size_t)INNER_ * DD * 2;
    unsigned short* WqTc = (unsigned short*)p; p += (size_t)INNER_ * DD * 2;
    unsigned short* WkTc = (unsigned short*)p; p += (size_t)INNER_ * DD * 2;
    unsigned short* WvTc = (unsigned short*)p; p += (size_t)INNER_ * DD * 2;
    unsigned short* WoTs = (unsigned short*)p; p += (size_t)DD * INNER_ * 2;
    unsigned short* WoTc = (unsigned short*)p; p += (size_t)DD * INNER_ * 2;
    unsigned short* WfcT = (unsigned short*)p; p += (size_t)VPAD * DD * 2;
    float* h1 = (float*)p;             p += (size_t)ROWS * DD * 4;
    unsigned char* tgtpad = (unsigned char*)p; p += ROWS;
    unsigned char* srcpad = (unsigned char*)p; p += SROWS;
    p = (char*)(((size_t)p + 15) & ~(size_t)15);
    int* rowmap = (int*)p;             p += (size_t)ROWS * 4;

    // ---------------- d_out scratch (289.4 MB < 312.2 MB, dead before logits) ----
    unsigned short* ob = (unsigned short*)d_out;
    unsigned short* Oall = ob;                       // [3072][16384]  100.7 MB
    unsigned short* Qg   = ob + 50331648;            // [3072][8192]    50.3 MB
    unsigned short* Kg   = ob + 75497472;            // [3072][8192]    50.3 MB
    unsigned short* Vt   = ob + 100663296;           // [8192][3072]^T  50.3 MB
    unsigned short* simb = ob + 125829120;           // [8][1536][1536] 37.7 MB

    // ---------------- prep ----------------
    embed_kernel<<<dim3(TT, BB), 256, 0, stream>>>(t1, t2, emb, x, xb, tgtpad);
    srcmask_kernel<<<dim3(SROWS / 256), 256, 0, stream>>>(src_ids, srcpad);
    rowmap_kernel<<<dim3(ROWS / 256), 256, 0, stream>>>(rowmap);
    conv_bf16<<<dim3((SROWS * DD) / 256), 256, 0, stream>>>(enc, encb, SROWS * DD);

    dim3 tcb(32, 8);
    transpose_conv<<<dim3(8, 512), tcb, 0, stream>>>(Wq_s, WqTs, DD, INNER_, INNER_);
    transpose_conv<<<dim3(8, 512), tcb, 0, stream>>>(Wk_s, WkTs, DD, INNER_, INNER_);
    transpose_conv<<<dim3(8, 512), tcb, 0, stream>>>(Wv_s, WvTs, DD, INNER_, INNER_);
    transpose_conv<<<dim3(8, 512), tcb, 0, stream>>>(Wq_c, WqTc, DD, INNER_, INNER_);
    transpose_conv<<<dim3(8, 512), tcb, 0, stream>>>(Wk_c, WkTc, DD, INNER_, INNER_);
    transpose_conv<<<dim3(8, 512), tcb, 0, stream>>>(Wv_c, WvTc, DD, INNER_, INNER_);
    transpose_conv<<<dim3(512, 8), tcb, 0, stream>>>(Wo_s, WoTs, INNER_, DD, DD);
    transpose_conv<<<dim3(512, 8), tcb, 0, stream>>>(Wo_c, WoTc, INNER_, DD, DD);
    transpose_conv<<<dim3(8, VPAD / 32), tcb, 0, stream>>>(Wfc, WfcT, DD, VV, VPAD);

    const float scale = 0.022097086912079608f;  // DH^-0.5
    const long long Z0 = 0;

    // ---------------- self attention (2 groups of 4 heads) ----------------
    hipMemsetAsync(aout, 0, (size_t)ROWS * DD * sizeof(float), stream);
    for (int g = 0; g < 2; ++g) {
        const size_t wof = (size_t)g * GN * DD;
        gemm_bt<0, 1><<<dim3(24, 64, 1), 256, 0, stream>>>(
            xb, DD, WqTs + wof, DD, Qg, GN, ROWS, GN, DD, 1.f, 0,
            Z0, Z0, Z0, Z0, Z0, Z0, nullptr, nullptr);
        gemm_bt<0, 1><<<dim3(24, 64, 1), 256, 0, stream>>>(
            xb, DD, WkTs + wof, DD, Kg, GN, ROWS, GN, DD, 1.f, 0,
            Z0, Z0, Z0, Z0, Z0, Z0, nullptr, nullptr);
        gemm_bt<1, 1><<<dim3(24, 64, 1), 256, 0, stream>>>(
            xb, DD, WvTs + wof, DD, Vt, ROWS, ROWS, GN, DD, 1.f, 0,
            Z0, Z0, Z0, Z0, Z0, Z0, nullptr, nullptr);
        // QK^T: z = b*4 + h (4 heads in group)
        gemm_bt<0, 1><<<dim3(12, 12, 8), 256, 0, stream>>>(
            Qg, GN, Kg, GN, simb, TT, TT, TT, DHD, scale, 2,
            (long long)TT * GN, DHD, (long long)TT * GN, DHD,
            4LL * TT * TT, (long long)TT * TT, nullptr, nullptr);
        softmax_bf16<6><<<dim3(TT, 8), 256, 0, stream>>>(simb, tgtpad, 2);
        // PV
        gemm_bt<0, 1><<<dim3(12, 16, 8), 256, 0, stream>>>(
            simb, TT, Vt, ROWS, Oall + (size_t)g * GN, INNER_, TT, DHD, TT, 1.f, 2,
            4LL * TT * TT, (long long)TT * TT,
            (long long)TT, (long long)DHD * ROWS,
            (long long)TT * INNER_, (long long)DHD, nullptr, nullptr);
    }
    gemm_bt<3, 8><<<dim3(24, 2, 8), 256, 0, stream>>>(
        Oall, INNER_, WoTs, INNER_, aout, DD, ROWS, DD, INNER_, 1.f, 0,
        Z0, Z0, Z0, Z0, Z0, Z0, nullptr, nullptr);
    ln_kernel<<<dim3(ROWS), 256, 0, stream>>>(x, aout, bo_s, g1, be1, xb);

    // ---------------- cross attention ----------------
    hipMemsetAsync(aout, 0, (size_t)ROWS * DD * sizeof(float), stream);
    for (int g = 0; g < 2; ++g) {
        const size_t wof = (size_t)g * GN * DD;
        gemm_bt<0, 1><<<dim3(24, 64, 1), 256, 0, stream>>>(
            xb, DD, WqTc + wof, DD, Qg, GN, ROWS, GN, DD, 1.f, 0,
            Z0, Z0, Z0, Z0, Z0, Z0, nullptr, nullptr);
        gemm_bt<0, 1><<<dim3(16, 64, 1), 256, 0, stream>>>(
            encb, DD, WkTc + wof, DD, Kg, GN, SROWS, GN, DD, 1.f, 0,
            Z0, Z0, Z0, Z0, Z0, Z0, nullptr, nullptr);
        gemm_bt<1, 1><<<dim3(16, 64, 1), 256, 0, stream>>>(
            encb, DD, WvTc + wof, DD, Vt, SROWS, SROWS, GN, DD, 1.f, 0,
            Z0, Z0, Z0, Z0, Z0, Z0, nullptr, nullptr);
        gemm_bt<0, 1><<<dim3(12, 8, 8), 256, 0, stream>>>(
            Qg, GN, Kg, GN, simb, SS, TT, SS, DHD, scale, 2,
            (long long)TT * GN, DHD, (long long)SS * GN, DHD,
            4LL * TT * SS, (long long)TT * SS, nullptr, nullptr);
        softmax_bf16<4><<<dim3(TT, 8), 256, 0, stream>>>(simb, srcpad, 2);
        gemm_bt<0, 1><<<dim3(12, 16, 8), 256, 0, stream>>>(
            simb, SS, Vt, SROWS, Oall + (size_t)g * GN, INNER_, TT, DHD, SS, 1.f, 2,
            4LL * TT * SS, (long long)TT * SS,
            (long long)SS, (long long)DHD * SROWS,
            (long long)TT * INNER_, (long long)DHD, nullptr, nullptr);
    }
    gemm_bt<3, 8><<<dim3(24, 2, 8), 256, 0, stream>>>(
        Oall, INNER_, WoTc, INNER_, aout, DD, ROWS, DD, INNER_, 1.f, 0,
        Z0, Z0, Z0, Z0, Z0, Z0, nullptr, nullptr);
    ln_kernel<<<dim3(ROWS), 256, 0, stream>>>(x, aout, bo_c, g2v, be2, xb);

    // ---------------- FFN (D->D->D, exact GELU), fp32 ----------------
    sgemm_small<<<dim3(ROWS / 64, DD / 64, 1), 256, 0, stream>>>(
        x, DD, W1, DD, h1, DD, ROWS, DD, DD, 2, b1);
    sgemm_small<<<dim3(ROWS / 64, DD / 64, 1), 256, 0, stream>>>(
        h1, DD, W2, DD, aout, DD, ROWS, DD, DD, 0, nullptr);
    ln_kernel<<<dim3(ROWS), 256, 0, stream>>>(x, aout, b2, g3, be3, xb);

    // ---------------- logits (bf16 MFMA, rowmap drops t==0 rows) ----------------
    gemm_bt<2, 1><<<dim3(24, VPAD / 128, 1), 256, 0, stream>>>(
        xb, DD, WfcT, DD, d_out, VV, ROWS, VV, DD, 1.f, 0,
        Z0, Z0, Z0, Z0, Z0, Z0, bfc, rowmap);

    // ---------------- second output: x[:,0,:] ----------------
    copycls_kernel<<<dim3(BB), 256, 0, stream>>>(
        x, (float*)d_out + (long long)BB * (TT - 1) * VV);
}

// Round 6
// 706.084 us; speedup vs baseline: 24.2744x; 2.2908x over previous
//
#include <hip/hip_runtime.h>
#include <hip/hip_bf16.h>
#include <float.h>
#include <math.h>

// ---------------- problem constants ----------------
#define BB 2
#define SS 1024
#define LL 767
#define TT 1536          // 2*(LL+1)
#define DD 256
#define HH 8
#define DHD 2048
#define INNER_ 16384
#define VV 25426
#define VPAD 25472
#define CLS_TOK 25426
#define MASK_TOKEN 25428
#define ROWS (BB*TT)     // 3072
#define SROWS (BB*SS)    // 2048

typedef __attribute__((ext_vector_type(8))) __bf16 bf16x8;
typedef __attribute__((ext_vector_type(4))) float f32x4;

__device__ __forceinline__ unsigned short f2bu(float f) {
    union { float f; unsigned u; } v; v.f = f;
    unsigned r = v.u + 0x7fff + ((v.u >> 16) & 1);
    return (unsigned short)(r >> 16);
}
__device__ __forceinline__ float bu2f(unsigned short u) {
    union { unsigned u; float f; } v; v.u = ((unsigned)u) << 16;
    return v.f;
}

__device__ __forceinline__ void gload16(const void* g, void* l) {
    __builtin_amdgcn_global_load_lds(
        (const __attribute__((address_space(1))) void*)g,
        (__attribute__((address_space(3))) void*)l, 16, 0, 0);
}

// ---------------- small helper kernels ----------------

__global__ __launch_bounds__(256) void embed_kernel(
    const int* __restrict__ t1, const int* __restrict__ t2,
    const float* __restrict__ emb, float* __restrict__ x,
    unsigned short* __restrict__ xb, unsigned char* __restrict__ tgt_pad)
{
    int t = blockIdx.x, b = blockIdx.y, d = threadIdx.x;
    int raw;
    if (t == 0)            raw = CLS_TOK;
    else if (t <= LL)      raw = t1[b * LL + (t - 1)];
    else if (t == LL + 1)  raw = CLS_TOK;
    else                   raw = t2[b * LL + (t - LL - 2)];
    int id = (raw == 0 || raw == MASK_TOKEN) ? MASK_TOKEN : raw;
    int i = d >> 1;
    float ang = (float)t * expf(-0.03597789208f * (float)(2 * i));
    float pe = (d & 1) ? cosf(ang) : sinf(ang);
    float val = 2.f * emb[(long long)id * DD + d] + pe;
    long long idx = ((long long)(b * TT + t)) * DD + d;
    x[idx] = val;
    xb[idx] = f2bu(val);
    if (d == 0) tgt_pad[b * TT + t] = (raw == 0) ? 1 : 0;
}

__global__ __launch_bounds__(256) void srcmask_kernel(
    const int* __restrict__ src, unsigned char* __restrict__ m)
{
    int i = blockIdx.x * 256 + threadIdx.x;
    if (i < SROWS) m[i] = (src[i] == 0) ? 1 : 0;
}

__global__ __launch_bounds__(256) void rowmap_kernel(int* __restrict__ rm)
{
    int r = blockIdx.x * 256 + threadIdx.x;
    if (r >= ROWS) return;
    int b = r / TT, t = r % TT;
    rm[r] = (t == 0) ? -1 : (b * (TT - 1) + t - 1);
}

__global__ __launch_bounds__(256) void copycls_kernel(
    const float* __restrict__ x, float* __restrict__ out2)
{
    int b = blockIdx.x, d = threadIdx.x;
    out2[b * DD + d] = x[(long long)b * TT * DD + d];
}

__global__ __launch_bounds__(256) void conv_bf16(
    const float* __restrict__ in, unsigned short* __restrict__ out, int n)
{
    int i = blockIdx.x * 256 + threadIdx.x;
    if (i < n) out[i] = f2bu(in[i]);
}

// transpose + convert: out[n][k] = bf16(in[k][n]); in [R][Cin] f32, out [Nout][R] bf16.
__global__ __launch_bounds__(256) void transpose_conv(
    const float* __restrict__ in, unsigned short* __restrict__ out,
    int R, int Cin, int Nout)
{
    __shared__ float t[32][33];
    int k0 = blockIdx.x * 32, n0 = blockIdx.y * 32;
#pragma unroll
    for (int i = 0; i < 4; ++i) {
        int k = k0 + threadIdx.y + i * 8;
        int n = n0 + threadIdx.x;
        t[threadIdx.y + i * 8][threadIdx.x] = (n < Cin) ? in[(size_t)k * Cin + n] : 0.f;
    }
    __syncthreads();
#pragma unroll
    for (int i = 0; i < 4; ++i) {
        int n = n0 + threadIdx.y + i * 8;
        int k = k0 + threadIdx.x;
        out[(size_t)n * R + k] = f2bu(t[threadIdx.x][threadIdx.y + i * 8]);
    }
}

// ---------------- bf16 MFMA GEMM (BT form, z-batched) ----------------
// C[M,N] = alpha * A[M,K] * B[N,K]^T. A,B bf16 row-major, K-contiguous.
// 128x128 tile, BK=32, 4 waves, global_load_lds staging with slot-XOR swizzle.
// SPLITK==1: zb = z>>zs, zh = z & ((1<<zs)-1); offsets zb*s?b + zh*s?h.
// SPLITK>1 (power of 2): kidx = z & (SPLITK-1), zh = z>>log2(SPLITK);
//   offsets zh*s?h only; K-chunk = kidx. STORE must be 3 (atomic).
// STORE: 0 = bf16 C (+czoff); 2 = fp32 C + bias + rowmap; 3 = fp32 atomicAdd.
template<int STORE, int SPLITK>
__global__ __launch_bounds__(256) void gemm_bt(
    const unsigned short* __restrict__ A, int lda,
    const unsigned short* __restrict__ B, int ldb,
    void* __restrict__ Cv, int ldc,
    int M, int N, int K, float alpha, int zs,
    long long sAb, long long sAh, long long sBb, long long sBh,
    long long sCb, long long sCh,
    const float* __restrict__ bias, const int* __restrict__ rowmap)
{
    __shared__ unsigned short As[4096];  // 128 rows x 32 k (8 KB), slot-swizzled
    __shared__ unsigned short Bs[4096];
    const int tid = threadIdx.x;
    const int w = tid >> 6, l = tid & 63;
    const int m0 = blockIdx.x * 128, n0 = blockIdx.y * 128;

    int kbeg = 0, kend = K;
    long long czoff = 0;
    if (SPLITK > 1) {
        constexpr int KSH = (SPLITK == 8) ? 3 : (SPLITK == 4) ? 2 : (SPLITK == 2) ? 1 : 0;
        int kidx = blockIdx.z & (SPLITK - 1);
        int zh = blockIdx.z >> KSH;
        int kc = K / SPLITK;
        kbeg = kidx * kc; kend = kbeg + kc;
        A += zh * sAh;
        B += zh * sBh;
        czoff = zh * sCh;
    } else {
        int zb = blockIdx.z >> zs;
        int zh = blockIdx.z - (zb << zs);
        A += zb * sAb + zh * sAh;
        B += zb * sBb + zh * sBh;
        czoff = zb * sCb + zh * sCh;
    }

    const int wr = (w >> 1) << 6, wc = (w & 1) << 6;
    const int lrow = l & 15, lk = l >> 4;

    // staging source mapping: LDS byte o = w*2048 + j*1024 + l*16
    // row r = o/64, lds slot s' = (o/16)&3, global slot = s' ^ ((r>>1)&3)
    const int o0 = (w << 11) + (l << 4);
    const int r0s = o0 >> 6;
    const int k0off = (((o0 >> 4) & 3) ^ ((r0s >> 1) & 3)) << 3;
    const int o1 = o0 + 1024;
    const int r1s = o1 >> 6;
    const int k1off = (((o1 >> 4) & 3) ^ ((r1s >> 1) & 3)) << 3;

    f32x4 acc[4][4];
#pragma unroll
    for (int mi = 0; mi < 4; ++mi)
#pragma unroll
        for (int ni = 0; ni < 4; ++ni)
            acc[mi][ni] = (f32x4){0.f, 0.f, 0.f, 0.f};

    const int rdslot = (lk ^ ((lrow >> 1) & 3)) << 4;  // frag-read swizzled slot byte

    for (int kt = kbeg; kt < kend; kt += 32) {
        gload16(A + (size_t)(m0 + r0s) * lda + kt + k0off, (char*)As + (w << 11));
        gload16(A + (size_t)(m0 + r1s) * lda + kt + k1off, (char*)As + (w << 11) + 1024);
        gload16(B + (size_t)(n0 + r0s) * ldb + kt + k0off, (char*)Bs + (w << 11));
        gload16(B + (size_t)(n0 + r1s) * ldb + kt + k1off, (char*)Bs + (w << 11) + 1024);
        __syncthreads();

        bf16x8 af[4], bfr[4];
#pragma unroll
        for (int mi = 0; mi < 4; ++mi) {
            int ra = wr + (mi << 4) + lrow;
            af[mi] = *reinterpret_cast<const bf16x8*>((const char*)As + (ra << 6) + rdslot);
        }
#pragma unroll
        for (int ni = 0; ni < 4; ++ni) {
            int rb = wc + (ni << 4) + lrow;
            bfr[ni] = *reinterpret_cast<const bf16x8*>((const char*)Bs + (rb << 6) + rdslot);
        }
#pragma unroll
        for (int mi = 0; mi < 4; ++mi)
#pragma unroll
            for (int ni = 0; ni < 4; ++ni)
                acc[mi][ni] = __builtin_amdgcn_mfma_f32_16x16x32_bf16(
                    af[mi], bfr[ni], acc[mi][ni], 0, 0, 0);
        __syncthreads();
    }

    // C/D layout: col = lane&15, row = (lane>>4)*4 + reg
    if (STORE == 0) {
        unsigned short* C = (unsigned short*)Cv + czoff;
#pragma unroll
        for (int mi = 0; mi < 4; ++mi) {
            int r = m0 + wr + (mi << 4) + (lk << 2);
#pragma unroll
            for (int ni = 0; ni < 4; ++ni) {
                int c = n0 + wc + (ni << 4) + lrow;
#pragma unroll
                for (int q = 0; q < 4; ++q)
                    C[(size_t)(r + q) * ldc + c] = f2bu(acc[mi][ni][q] * alpha);
            }
        }
    } else if (STORE == 2) {
        float* C = (float*)Cv;
#pragma unroll
        for (int mi = 0; mi < 4; ++mi) {
            int r = m0 + wr + (mi << 4) + (lk << 2);
#pragma unroll
            for (int q = 0; q < 4; ++q) {
                int rm = rowmap[r + q];
                if (rm < 0) continue;
#pragma unroll
                for (int ni = 0; ni < 4; ++ni) {
                    int c = n0 + wc + (ni << 4) + lrow;
                    if (c < N) C[(size_t)rm * ldc + c] = acc[mi][ni][q] * alpha + bias[c];
                }
            }
        }
    } else {
        float* C = (float*)Cv + czoff;
#pragma unroll
        for (int mi = 0; mi < 4; ++mi) {
            int r = m0 + wr + (mi << 4) + (lk << 2);
#pragma unroll
            for (int ni = 0; ni < 4; ++ni) {
                int c = n0 + wc + (ni << 4) + lrow;
#pragma unroll
                for (int q = 0; q < 4; ++q)
                    atomicAdd(&C[(size_t)(r + q) * ldc + c], acc[mi][ni][q] * alpha);
            }
        }
    }
}

// ---------------- masked row softmax on bf16, z-batched over (b,h) ----------------
template<int CNT>
__global__ __launch_bounds__(256) void softmax_bf16(
    unsigned short* __restrict__ S, const unsigned char* __restrict__ mask, int zs)
{
    __shared__ float red[4];
    const int z = blockIdx.y;
    unsigned short* p = S + ((long long)z * TT + blockIdx.x) * (CNT * 256);
    const unsigned char* mk = mask + (long long)(z >> zs) * (CNT * 256);
    const int tid = threadIdx.x;

    float v[CNT];
    float mx = -FLT_MAX;
#pragma unroll
    for (int c = 0; c < CNT; ++c) {
        int j = (c << 8) + tid;
        float s = bu2f(p[j]);
        if (mk[j]) s = -FLT_MAX;
        v[c] = s;
        mx = fmaxf(mx, s);
    }
#pragma unroll
    for (int off = 32; off > 0; off >>= 1) mx = fmaxf(mx, __shfl_down(mx, off));
    if ((tid & 63) == 0) red[tid >> 6] = mx;
    __syncthreads();
    mx = fmaxf(fmaxf(red[0], red[1]), fmaxf(red[2], red[3]));
    __syncthreads();

    float sum = 0.f;
#pragma unroll
    for (int c = 0; c < CNT; ++c) {
        float e = expf(v[c] - mx);
        v[c] = e;
        sum += e;
    }
#pragma unroll
    for (int off = 32; off > 0; off >>= 1) sum += __shfl_down(sum, off);
    if ((tid & 63) == 0) red[tid >> 6] = sum;
    __syncthreads();
    sum = red[0] + red[1] + red[2] + red[3];
    float inv = 1.f / sum;
#pragma unroll
    for (int c = 0; c < CNT; ++c) p[(c << 8) + tid] = f2bu(v[c] * inv);
}

// ---------------- residual + LayerNorm (in place on x, emits bf16 copy) ----------------
__global__ __launch_bounds__(256) void ln_kernel(
    float* __restrict__ x, const float* __restrict__ a,
    const float* __restrict__ abias,
    const float* __restrict__ g, const float* __restrict__ be,
    unsigned short* __restrict__ xb)
{
    __shared__ float red[4];
    const long long r = blockIdx.x;
    const int d = threadIdx.x;
    const long long idx = r * DD + d;
    float v = x[idx] + a[idx];
    if (abias) v += abias[d];

    float s = v;
#pragma unroll
    for (int off = 32; off > 0; off >>= 1) s += __shfl_down(s, off);
    if ((d & 63) == 0) red[d >> 6] = s;
    __syncthreads();
    float mean = (red[0] + red[1] + red[2] + red[3]) * (1.f / DD);
    __syncthreads();

    float df = v - mean;
    float s2 = df * df;
#pragma unroll
    for (int off = 32; off > 0; off >>= 1) s2 += __shfl_down(s2, off);
    if ((d & 63) == 0) red[d >> 6] = s2;
    __syncthreads();
    float var = (red[0] + red[1] + red[2] + red[3]) * (1.f / DD);

    float o = df / sqrtf(var + 1e-5f) * g[d] + be[d];
    x[idx] = o;
    xb[idx] = f2bu(o);
}

// ---------------- small fp32 SGEMM for FFN ----------------
__global__ __launch_bounds__(256) void sgemm_small(
    const float* __restrict__ A, int lda,
    const float* __restrict__ Bm, int ldb,
    float* __restrict__ C, int ldc,
    int M, int N, int K, int mode, const float* __restrict__ bias)
{
    __shared__ float As[16][64];
    __shared__ float Bs[16][64];
    const int tid = threadIdx.x;
    const int tx = tid & 15, ty = tid >> 4;
    const int m0 = blockIdx.x * 64;
    const int n0 = blockIdx.y * 64;
    const int ar = tid >> 2, ak = (tid & 3) * 4;
    const int bk = tid >> 4, bn = (tid & 15) * 4;

    float acc[4][4];
#pragma unroll
    for (int i = 0; i < 4; ++i)
#pragma unroll
        for (int j = 0; j < 4; ++j) acc[i][j] = 0.f;

    for (int kt = 0; kt < K; kt += 16) {
        {
            const float4 va = *reinterpret_cast<const float4*>(
                A + (long long)(m0 + ar) * lda + (kt + ak));
            As[ak + 0][ar] = va.x; As[ak + 1][ar] = va.y;
            As[ak + 2][ar] = va.z; As[ak + 3][ar] = va.w;
        }
        {
            const float4 vb = *reinterpret_cast<const float4*>(
                Bm + (long long)(kt + bk) * ldb + (n0 + bn));
            *reinterpret_cast<float4*>(&Bs[bk][bn]) = vb;
        }
        __syncthreads();
#pragma unroll
        for (int k = 0; k < 16; ++k) {
            float a[4], b[4];
#pragma unroll
            for (int i = 0; i < 4; ++i) a[i] = As[k][ty + i * 16];
#pragma unroll
            for (int j = 0; j < 4; ++j) b[j] = Bs[k][tx + j * 16];
#pragma unroll
            for (int i = 0; i < 4; ++i)
#pragma unroll
                for (int j = 0; j < 4; ++j)
                    acc[i][j] = fmaf(a[i], b[j], acc[i][j]);
        }
        __syncthreads();
    }

#pragma unroll
    for (int i = 0; i < 4; ++i) {
        int r = m0 + ty + i * 16;
        float* crow = C + (long long)r * ldc;
#pragma unroll
        for (int j = 0; j < 4; ++j) {
            int n = n0 + tx + j * 16;
            float v = acc[i][j];
            if (mode >= 1) v += bias[n];
            if (mode == 2) v = 0.5f * v * (1.f + erff(v * 0.70710678118f));
            crow[n] = v;
        }
    }
}

// ---------------- launch ----------------
extern "C" void kernel_launch(void* const* d_in, const int* in_sizes, int n_in,
                              void* d_out, int out_size, void* d_ws, size_t ws_size,
                              hipStream_t stream)
{
    const int*   src_ids = (const int*)d_in[0];
    const int*   t1      = (const int*)d_in[1];
    const int*   t2      = (const int*)d_in[2];
    const float* enc  = (const float*)d_in[4];
    const float* emb  = (const float*)d_in[5];
    const float* Wq_s = (const float*)d_in[6];
    const float* Wk_s = (const float*)d_in[7];
    const float* Wv_s = (const float*)d_in[8];
    const float* Wo_s = (const float*)d_in[9];
    const float* bo_s = (const float*)d_in[10];
    const float* Wq_c = (const float*)d_in[11];
    const float* Wk_c = (const float*)d_in[12];
    const float* Wv_c = (const float*)d_in[13];
    const float* Wo_c = (const float*)d_in[14];
    const float* bo_c = (const float*)d_in[15];
    const float* W1   = (const float*)d_in[16];
    const float* b1   = (const float*)d_in[17];
    const float* W2   = (const float*)d_in[18];
    const float* b2   = (const float*)d_in[19];
    const float* g1   = (const float*)d_in[20];
    const float* g2v  = (const float*)d_in[21];
    const float* g3   = (const float*)d_in[22];
    const float* be1  = (const float*)d_in[23];
    const float* be2  = (const float*)d_in[24];
    const float* be3  = (const float*)d_in[25];
    const float* Wfc  = (const float*)d_in[26];
    const float* bfc  = (const float*)d_in[27];

    // ---------------- d_ws layout (~106 MB) ----------------
    char* p = (char*)d_ws;
    float* x    = (float*)p;           p += (size_t)ROWS * DD * 4;
    float* aout = (float*)p;           p += (size_t)ROWS * DD * 4;
    float* h1   = (float*)p;           p += (size_t)ROWS * DD * 4;
    unsigned short* xb   = (unsigned short*)p; p += (size_t)ROWS * DD * 2;
    unsigned short* xT   = (unsigned short*)p; p += (size_t)DD * ROWS * 2;   // [256][3072]
    unsigned short* encb = (unsigned short*)p; p += (size_t)SROWS * DD * 2;
    unsigned short* encT = (unsigned short*)p; p += (size_t)DD * SROWS * 2;  // [256][2048]
    unsigned short* Wqb_s = (unsigned short*)p; p += (size_t)DD * INNER_ * 2;
    unsigned short* Wkb_s = (unsigned short*)p; p += (size_t)DD * INNER_ * 2;
    unsigned short* Wvb_s = (unsigned short*)p; p += (size_t)DD * INNER_ * 2;
    unsigned short* Wqb_c = (unsigned short*)p; p += (size_t)DD * INNER_ * 2;
    unsigned short* Wkb_c = (unsigned short*)p; p += (size_t)DD * INNER_ * 2;
    unsigned short* Wvb_c = (unsigned short*)p; p += (size_t)DD * INNER_ * 2;
    unsigned short* WoTs  = (unsigned short*)p; p += (size_t)DD * INNER_ * 2;
    unsigned short* WoTc  = (unsigned short*)p; p += (size_t)DD * INNER_ * 2;
    unsigned short* WfcT  = (unsigned short*)p; p += (size_t)VPAD * DD * 2;
    unsigned short* MtNb  = (unsigned short*)p; p += (size_t)4 * 524288 * 2; // 4 quarters
    unsigned char* tgtpad = (unsigned char*)p; p += ROWS;
    unsigned char* srcpad = (unsigned char*)p; p += SROWS;
    p = (char*)(((size_t)p + 15) & ~(size_t)15);
    int* rowmap = (int*)p;             p += (size_t)ROWS * 4;

    // MtNb quarters (each 524288 elems): Mt_s, Nt_s, Mt_c, Nt_c
    unsigned short* Mtb_s = MtNb;
    unsigned short* Ntb_s = MtNb + 524288;
    unsigned short* Mtb_c = MtNb + 2 * 524288;
    unsigned short* Ntb_c = MtNb + 3 * 524288;

    // ---------------- d_out scratch (100.7 MB < 312 MB, dead before logits) ----
    unsigned short* ob = (unsigned short*)d_out;
    unsigned short* simS = ob;                    // [16][1536][1536] max (75.5 MB)
    unsigned short* Pb   = ob + 37748736;         // [8][3072][256]   (12.6 MB)
    unsigned short* Ub   = Pb + 6291456;          // [3072][2048]     (12.6 MB)
    float* MNacc = (float*)d_out;                 // [4][524288] f32, aliases simS (dead early)

    // ---------------- prep ----------------
    embed_kernel<<<dim3(TT, BB), 256, 0, stream>>>(t1, t2, emb, x, xb, tgtpad);
    srcmask_kernel<<<dim3(SROWS / 256), 256, 0, stream>>>(src_ids, srcpad);
    rowmap_kernel<<<dim3(ROWS / 256), 256, 0, stream>>>(rowmap);
    conv_bf16<<<dim3((SROWS * DD) / 256), 256, 0, stream>>>(enc, encb, SROWS * DD);

    dim3 tcb(32, 8);
    transpose_conv<<<dim3(ROWS / 32, 8), tcb, 0, stream>>>(x, xT, ROWS, DD, DD);
    transpose_conv<<<dim3(SROWS / 32, 8), tcb, 0, stream>>>(enc, encT, SROWS, DD, DD);
    conv_bf16<<<dim3((DD * INNER_) / 256), 256, 0, stream>>>(Wq_s, Wqb_s, DD * INNER_);
    conv_bf16<<<dim3((DD * INNER_) / 256), 256, 0, stream>>>(Wk_s, Wkb_s, DD * INNER_);
    conv_bf16<<<dim3((DD * INNER_) / 256), 256, 0, stream>>>(Wv_s, Wvb_s, DD * INNER_);
    conv_bf16<<<dim3((DD * INNER_) / 256), 256, 0, stream>>>(Wq_c, Wqb_c, DD * INNER_);
    conv_bf16<<<dim3((DD * INNER_) / 256), 256, 0, stream>>>(Wk_c, Wkb_c, DD * INNER_);
    conv_bf16<<<dim3((DD * INNER_) / 256), 256, 0, stream>>>(Wv_c, Wvb_c, DD * INNER_);
    transpose_conv<<<dim3(512, 8), tcb, 0, stream>>>(Wo_s, WoTs, INNER_, DD, DD);
    transpose_conv<<<dim3(512, 8), tcb, 0, stream>>>(Wo_c, WoTc, INNER_, DD, DD);
    transpose_conv<<<dim3(8, VPAD / 32), tcb, 0, stream>>>(Wfc, WfcT, DD, VV, VPAD);

    const float scale = 0.022097086912079608f;  // DH^-0.5
    const long long Z0 = 0;

    // ---------------- M/N precompute (rank-256 folding) ----------------
    // Mt_h = Wk_h @ Wq_h^T  (so P = x @ Mt^T gives x @ Wq_h Wk_h^T)
    // Nt[j][h*256+d] = N_h[d][j], N_h = Wv_h @ Wo_h
    hipMemsetAsync(MNacc, 0, (size_t)4 * 524288 * 4, stream);
    gemm_bt<3, 4><<<dim3(2, 2, 32), 256, 0, stream>>>(
        Wkb_s, INNER_, Wqb_s, INNER_, MNacc, 256, 256, 256, DHD, 1.f, 0,
        Z0, 2048, Z0, 2048, Z0, 65536, nullptr, nullptr);
    gemm_bt<3, 4><<<dim3(2, 2, 32), 256, 0, stream>>>(
        WoTs, INNER_, Wvb_s, INNER_, MNacc + 524288, 2048, 256, 256, DHD, 1.f, 0,
        Z0, 2048, Z0, 2048, Z0, 256, nullptr, nullptr);
    gemm_bt<3, 4><<<dim3(2, 2, 32), 256, 0, stream>>>(
        Wkb_c, INNER_, Wqb_c, INNER_, MNacc + 2 * 524288, 256, 256, 256, DHD, 1.f, 0,
        Z0, 2048, Z0, 2048, Z0, 65536, nullptr, nullptr);
    gemm_bt<3, 4><<<dim3(2, 2, 32), 256, 0, stream>>>(
        WoTc, INNER_, Wvb_c, INNER_, MNacc + 3 * 524288, 2048, 256, 256, DHD, 1.f, 0,
        Z0, 2048, Z0, 2048, Z0, 256, nullptr, nullptr);
    conv_bf16<<<dim3((4 * 524288) / 256), 256, 0, stream>>>(MNacc, MtNb, 4 * 524288);

    // ---------------- self attention ----------------
    hipMemsetAsync(aout, 0, (size_t)ROWS * DD * sizeof(float), stream);
    // P_h = x @ Mt_h^T : [8][3072][256]
    gemm_bt<0, 1><<<dim3(24, 2, 8), 256, 0, stream>>>(
        xb, DD, Mtb_s, DD, Pb, DD, ROWS, DD, DD, 1.f, 3,
        Z0, Z0, Z0, 65536, Z0, 786432, nullptr, nullptr);
    // sim = P_h @ x^T : z=(b,h), [16][1536][1536]
    gemm_bt<0, 1><<<dim3(12, 12, 16), 256, 0, stream>>>(
        Pb, DD, xb, DD, simS, TT, TT, TT, DD, scale, 3,
        393216, 786432, 393216, Z0,
        18874368, 2359296, nullptr, nullptr);
    softmax_bf16<6><<<dim3(TT, 16), 256, 0, stream>>>(simS, tgtpad, 3);
    // U_h = attn_h @ x : [3072][2048] (col block h*256)
    gemm_bt<0, 1><<<dim3(12, 2, 16), 256, 0, stream>>>(
        simS, TT, xT, ROWS, Ub, 2048, TT, DD, TT, 1.f, 3,
        18874368, 2359296, 1536, Z0,
        3145728, 256, nullptr, nullptr);
    // O = U @ Ncat (split-K=4, atomic into aout)
    gemm_bt<3, 4><<<dim3(24, 2, 4), 256, 0, stream>>>(
        Ub, 2048, Ntb_s, 2048, aout, DD, ROWS, DD, 2048, 1.f, 0,
        Z0, Z0, Z0, Z0, Z0, Z0, nullptr, nullptr);
    ln_kernel<<<dim3(ROWS), 256, 0, stream>>>(x, aout, bo_s, g1, be1, xb);

    // ---------------- cross attention ----------------
    hipMemsetAsync(aout, 0, (size_t)ROWS * DD * sizeof(float), stream);
    gemm_bt<0, 1><<<dim3(24, 2, 8), 256, 0, stream>>>(
        xb, DD, Mtb_c, DD, Pb, DD, ROWS, DD, DD, 1.f, 3,
        Z0, Z0, Z0, 65536, Z0, 786432, nullptr, nullptr);
    // sim = P_h @ enc^T : [16][1536][1024]
    gemm_bt<0, 1><<<dim3(12, 8, 16), 256, 0, stream>>>(
        Pb, DD, encb, DD, simS, SS, TT, SS, DD, scale, 3,
        393216, 786432, 262144, Z0,
        12582912, 1572864, nullptr, nullptr);
    softmax_bf16<4><<<dim3(TT, 16), 256, 0, stream>>>(simS, srcpad, 3);
    gemm_bt<0, 1><<<dim3(12, 2, 16), 256, 0, stream>>>(
        simS, SS, encT, SROWS, Ub, 2048, TT, DD, SS, 1.f, 3,
        12582912, 1572864, 1024, Z0,
        3145728, 256, nullptr, nullptr);
    gemm_bt<3, 4><<<dim3(24, 2, 4), 256, 0, stream>>>(
        Ub, 2048, Ntb_c, 2048, aout, DD, ROWS, DD, 2048, 1.f, 0,
        Z0, Z0, Z0, Z0, Z0, Z0, nullptr, nullptr);
    ln_kernel<<<dim3(ROWS), 256, 0, stream>>>(x, aout, bo_c, g2v, be2, xb);

    // ---------------- FFN (D->D->D, exact GELU), fp32 ----------------
    sgemm_small<<<dim3(ROWS / 64, DD / 64, 1), 256, 0, stream>>>(
        x, DD, W1, DD, h1, DD, ROWS, DD, DD, 2, b1);
    sgemm_small<<<dim3(ROWS / 64, DD / 64, 1), 256, 0, stream>>>(
        h1, DD, W2, DD, aout, DD, ROWS, DD, DD, 0, nullptr);
    ln_kernel<<<dim3(ROWS), 256, 0, stream>>>(x, aout, b2, g3, be3, xb);

    // ---------------- logits (bf16 MFMA, rowmap drops t==0 rows) ----------------
    gemm_bt<2, 1><<<dim3(24, VPAD / 128, 1), 256, 0, stream>>>(
        xb, DD, WfcT, DD, d_out, VV, ROWS, VV, DD, 1.f, 0,
        Z0, Z0, Z0, Z0, Z0, Z0, bfc, rowmap);

    // ---------------- second output: x[:,0,:] ----------------
    copycls_kernel<<<dim3(BB), 256, 0, stream>>>(
        x, (float*)d_out + (long long)BB * (TT - 1) * VV);
}

// Round 7
// 639.053 us; speedup vs baseline: 26.8206x; 1.1049x over previous
//
#include <hip/hip_runtime.h>
#include <hip/hip_bf16.h>
#include <float.h>
#include <math.h>

// ---------------- problem constants ----------------
#define BB 2
#define SS 1024
#define LL 767
#define TT 1536          // 2*(LL+1)
#define DD 256
#define HH 8
#define DHD 2048
#define INNER_ 16384
#define VV 25426
#define VPAD 25472
#define CLS_TOK 25426
#define MASK_TOKEN 25428
#define ROWS (BB*TT)     // 3072
#define SROWS (BB*SS)    // 2048

typedef __attribute__((ext_vector_type(8))) __bf16 bf16x8;
typedef __attribute__((ext_vector_type(4))) float f32x4;

__device__ __forceinline__ unsigned short f2bu(float f) {
    union { float f; unsigned u; } v; v.f = f;
    unsigned r = v.u + 0x7fff + ((v.u >> 16) & 1);
    return (unsigned short)(r >> 16);
}
__device__ __forceinline__ float bu2f(unsigned short u) {
    union { unsigned u; float f; } v; v.u = ((unsigned)u) << 16;
    return v.f;
}

__device__ __forceinline__ void gload16(const void* g, void* l) {
    __builtin_amdgcn_global_load_lds(
        (const __attribute__((address_space(1))) void*)g,
        (__attribute__((address_space(3))) void*)l, 16, 0, 0);
}

// ---------------- small helper kernels ----------------

__global__ __launch_bounds__(256) void embed_kernel(
    const int* __restrict__ t1, const int* __restrict__ t2,
    const float* __restrict__ emb, float* __restrict__ x,
    unsigned short* __restrict__ xb, unsigned char* __restrict__ tgt_pad)
{
    int t = blockIdx.x, b = blockIdx.y, d = threadIdx.x;
    int raw;
    if (t == 0)            raw = CLS_TOK;
    else if (t <= LL)      raw = t1[b * LL + (t - 1)];
    else if (t == LL + 1)  raw = CLS_TOK;
    else                   raw = t2[b * LL + (t - LL - 2)];
    int id = (raw == 0 || raw == MASK_TOKEN) ? MASK_TOKEN : raw;
    int i = d >> 1;
    float ang = (float)t * expf(-0.03597789208f * (float)(2 * i));
    float pe = (d & 1) ? cosf(ang) : sinf(ang);
    float val = 2.f * emb[(long long)id * DD + d] + pe;
    long long idx = ((long long)(b * TT + t)) * DD + d;
    x[idx] = val;
    xb[idx] = f2bu(val);
    if (d == 0) tgt_pad[b * TT + t] = (raw == 0) ? 1 : 0;
}

// src pad mask + rowmap in one launch (grid ROWS/256)
__global__ __launch_bounds__(256) void masks_kernel(
    const int* __restrict__ src, unsigned char* __restrict__ m, int* __restrict__ rm)
{
    int i = blockIdx.x * 256 + threadIdx.x;
    if (i < SROWS) m[i] = (src[i] == 0) ? 1 : 0;
    if (i < ROWS) {
        int b = i / TT, t = i % TT;
        rm[i] = (t == 0) ? -1 : (b * (TT - 1) + t - 1);
    }
}

__global__ __launch_bounds__(256) void copycls_kernel(
    const float* __restrict__ x, float* __restrict__ out2)
{
    int b = blockIdx.x, d = threadIdx.x;
    out2[b * DD + d] = x[(long long)b * TT * DD + d];
}

// vectorized f32 -> bf16 convert (4 elems/thread); n % 1024 == 0
__global__ __launch_bounds__(256) void conv_bf16v4(
    const float* __restrict__ in, unsigned short* __restrict__ out)
{
    size_t i = ((size_t)blockIdx.x * 256 + threadIdx.x) * 4;
    float4 v = *reinterpret_cast<const float4*>(in + i);
    ushort4 u;
    u.x = f2bu(v.x); u.y = f2bu(v.y); u.z = f2bu(v.z); u.w = f2bu(v.w);
    *reinterpret_cast<ushort4*>(out + i) = u;
}

// six weight matrices [DD][INNER_] f32 -> contiguous bf16 (one launch)
__global__ __launch_bounds__(256) void convW6(
    const float* __restrict__ w0, const float* __restrict__ w1,
    const float* __restrict__ w2, const float* __restrict__ w3,
    const float* __restrict__ w4, const float* __restrict__ w5,
    unsigned short* __restrict__ dst)
{
    int seg = blockIdx.y;
    const float* s = seg == 0 ? w0 : seg == 1 ? w1 : seg == 2 ? w2 :
                     seg == 3 ? w3 : seg == 4 ? w4 : w5;
    size_t i = ((size_t)blockIdx.x * 256 + threadIdx.x) * 4;
    float4 v = *reinterpret_cast<const float4*>(s + i);
    ushort4 u;
    u.x = f2bu(v.x); u.y = f2bu(v.y); u.z = f2bu(v.z); u.w = f2bu(v.w);
    *reinterpret_cast<ushort4*>(dst + (size_t)seg * ((size_t)DD * INNER_) + i) = u;
}

// transpose + convert: out[n][k] = bf16(in[k][n]); in [R][Cin] f32, out [Nout][R] bf16.
__global__ __launch_bounds__(256) void transpose_conv(
    const float* __restrict__ in, unsigned short* __restrict__ out,
    int R, int Cin, int Nout)
{
    __shared__ float t[32][33];
    int k0 = blockIdx.x * 32, n0 = blockIdx.y * 32;
#pragma unroll
    for (int i = 0; i < 4; ++i) {
        int k = k0 + threadIdx.y + i * 8;
        int n = n0 + threadIdx.x;
        t[threadIdx.y + i * 8][threadIdx.x] = (n < Cin) ? in[(size_t)k * Cin + n] : 0.f;
    }
    __syncthreads();
#pragma unroll
    for (int i = 0; i < 4; ++i) {
        int n = n0 + threadIdx.y + i * 8;
        int k = k0 + threadIdx.x;
        out[(size_t)n * R + k] = f2bu(t[threadIdx.x][threadIdx.y + i * 8]);
    }
}

// ---------------- bf16 MFMA GEMM (BT form, z-batched, BK=64) ----------------
// C[M,N] = alpha * A[M,K] * B[N,K]^T. A,B bf16 row-major, K-contiguous.
// 128x128 tile, BK=64, 4 waves, global_load_lds with 8-slot XOR swizzle
// (linear LDS dest + inverse-swizzled global source + swizzled frag read).
// SPLITK==1: zb = z>>zs, zh = z & ((1<<zs)-1); offsets zb*s?b + zh*s?h.
// SPLITK>1 (pow2): kidx = z & (SPLITK-1), zh = z>>log2(SPLITK); K-chunk = kidx.
// Requires M%128==0, (K/SPLITK)%64==0, lda/ldb%8==0, bases 16B-aligned.
// STORE: 0 = bf16 C (+czoff); 2 = fp32 C + bias + rowmap; 3 = fp32 atomicAdd.
template<int STORE, int SPLITK>
__global__ __launch_bounds__(256) void gemm_bt(
    const unsigned short* __restrict__ A, int lda,
    const unsigned short* __restrict__ B, int ldb,
    void* __restrict__ Cv, int ldc,
    int M, int N, int K, float alpha, int zs,
    long long sAb, long long sAh, long long sBb, long long sBh,
    long long sCb, long long sCh,
    const float* __restrict__ bias, const int* __restrict__ rowmap)
{
    __shared__ unsigned short As[8192];  // 128 rows x 64 k (16 KB), slot-swizzled
    __shared__ unsigned short Bs[8192];
    const int tid = threadIdx.x;
    const int w = tid >> 6, l = tid & 63;
    const int m0 = blockIdx.x * 128, n0 = blockIdx.y * 128;

    int kbeg = 0, kend = K;
    long long czoff = 0;
    if (SPLITK > 1) {
        constexpr int KSH = (SPLITK == 8) ? 3 : (SPLITK == 4) ? 2 : (SPLITK == 2) ? 1 : 0;
        int kidx = blockIdx.z & (SPLITK - 1);
        int zh = blockIdx.z >> KSH;
        int kc = K / SPLITK;
        kbeg = kidx * kc; kend = kbeg + kc;
        A += zh * sAh;
        B += zh * sBh;
        czoff = zh * sCh;
    } else {
        int zb = blockIdx.z >> zs;
        int zh = blockIdx.z - (zb << zs);
        A += zb * sAb + zh * sAh;
        B += zb * sBb + zh * sBh;
        czoff = zb * sCb + zh * sCh;
    }

    const int wr = (w >> 1) << 6, wc = (w & 1) << 6;
    const int lrow = l & 15, lk = l >> 4;

    // staging: round j writes LDS byte j*4096 + w*1024 + l*16.
    // row = off>>7 = j*32 + w*8 + (l>>3); lds slot = l&7;
    // global slot = (l&7) ^ (row&7) = (l&7) ^ (l>>3)  (j*32, w*8 are 8-multiples)
    const int sro = (w << 3) + (l >> 3);
    const int sko = (((l & 7) ^ (l >> 3)) << 3);
    const int ldst = (w << 10) + (l << 4);

    f32x4 acc[4][4];
#pragma unroll
    for (int mi = 0; mi < 4; ++mi)
#pragma unroll
        for (int ni = 0; ni < 4; ++ni)
            acc[mi][ni] = (f32x4){0.f, 0.f, 0.f, 0.f};

    for (int kt = kbeg; kt < kend; kt += 64) {
#pragma unroll
        for (int j = 0; j < 4; ++j)
            gload16(A + (size_t)(m0 + sro + j * 32) * lda + kt + sko,
                    (char*)As + (j << 12) + ldst);
#pragma unroll
        for (int j = 0; j < 4; ++j)
            gload16(B + (size_t)(n0 + sro + j * 32) * ldb + kt + sko,
                    (char*)Bs + (j << 12) + ldst);
        __syncthreads();

#pragma unroll
        for (int kk = 0; kk < 2; ++kk) {
            const int slot = (kk << 2) + lk;
            bf16x8 af[4], bfr[4];
#pragma unroll
            for (int mi = 0; mi < 4; ++mi) {
                int ra = wr + (mi << 4) + lrow;
                af[mi] = *reinterpret_cast<const bf16x8*>(
                    (const char*)As + (ra << 7) + ((slot ^ (ra & 7)) << 4));
            }
#pragma unroll
            for (int ni = 0; ni < 4; ++ni) {
                int rb = wc + (ni << 4) + lrow;
                bfr[ni] = *reinterpret_cast<const bf16x8*>(
                    (const char*)Bs + (rb << 7) + ((slot ^ (rb & 7)) << 4));
            }
#pragma unroll
            for (int mi = 0; mi < 4; ++mi)
#pragma unroll
                for (int ni = 0; ni < 4; ++ni)
                    acc[mi][ni] = __builtin_amdgcn_mfma_f32_16x16x32_bf16(
                        af[mi], bfr[ni], acc[mi][ni], 0, 0, 0);
        }
        __syncthreads();
    }

    // C/D layout: col = lane&15, row = (lane>>4)*4 + reg
    if (STORE == 0) {
        unsigned short* C = (unsigned short*)Cv + czoff;
#pragma unroll
        for (int mi = 0; mi < 4; ++mi) {
            int r = m0 + wr + (mi << 4) + (lk << 2);
#pragma unroll
            for (int ni = 0; ni < 4; ++ni) {
                int c = n0 + wc + (ni << 4) + lrow;
#pragma unroll
                for (int q = 0; q < 4; ++q)
                    C[(size_t)(r + q) * ldc + c] = f2bu(acc[mi][ni][q] * alpha);
            }
        }
    } else if (STORE == 2) {
        float* C = (float*)Cv;
#pragma unroll
        for (int mi = 0; mi < 4; ++mi) {
            int r = m0 + wr + (mi << 4) + (lk << 2);
#pragma unroll
            for (int q = 0; q < 4; ++q) {
                int rm = rowmap[r + q];
                if (rm < 0) continue;
#pragma unroll
                for (int ni = 0; ni < 4; ++ni) {
                    int c = n0 + wc + (ni << 4) + lrow;
                    if (c < N) C[(size_t)rm * ldc + c] = acc[mi][ni][q] * alpha + bias[c];
                }
            }
        }
    } else {
        float* C = (float*)Cv + czoff;
#pragma unroll
        for (int mi = 0; mi < 4; ++mi) {
            int r = m0 + wr + (mi << 4) + (lk << 2);
#pragma unroll
            for (int ni = 0; ni < 4; ++ni) {
                int c = n0 + wc + (ni << 4) + lrow;
#pragma unroll
                for (int q = 0; q < 4; ++q)
                    atomicAdd(&C[(size_t)(r + q) * ldc + c], acc[mi][ni][q] * alpha);
            }
        }
    }
}

// ---------------- masked row softmax on bf16, z-batched over (b,h) ----------------
template<int CNT>
__global__ __launch_bounds__(256) void softmax_bf16(
    unsigned short* __restrict__ S, const unsigned char* __restrict__ mask, int zs)
{
    __shared__ float red[4];
    const int z = blockIdx.y;
    unsigned short* p = S + ((long long)z * TT + blockIdx.x) * (CNT * 256);
    const unsigned char* mk = mask + (long long)(z >> zs) * (CNT * 256);
    const int tid = threadIdx.x;

    float v[CNT];
    float mx = -FLT_MAX;
#pragma unroll
    for (int c = 0; c < CNT; ++c) {
        int j = (c << 8) + tid;
        float s = bu2f(p[j]);
        if (mk[j]) s = -FLT_MAX;
        v[c] = s;
        mx = fmaxf(mx, s);
    }
#pragma unroll
    for (int off = 32; off > 0; off >>= 1) mx = fmaxf(mx, __shfl_down(mx, off));
    if ((tid & 63) == 0) red[tid >> 6] = mx;
    __syncthreads();
    mx = fmaxf(fmaxf(red[0], red[1]), fmaxf(red[2], red[3]));
    __syncthreads();

    float sum = 0.f;
#pragma unroll
    for (int c = 0; c < CNT; ++c) {
        float e = expf(v[c] - mx);
        v[c] = e;
        sum += e;
    }
#pragma unroll
    for (int off = 32; off > 0; off >>= 1) sum += __shfl_down(sum, off);
    if ((tid & 63) == 0) red[tid >> 6] = sum;
    __syncthreads();
    sum = red[0] + red[1] + red[2] + red[3];
    float inv = 1.f / sum;
#pragma unroll
    for (int c = 0; c < CNT; ++c) p[(c << 8) + tid] = f2bu(v[c] * inv);
}

// ---------------- residual + LayerNorm (in place on x, emits bf16 copy) ----------------
__global__ __launch_bounds__(256) void ln_kernel(
    float* __restrict__ x, const float* __restrict__ a,
    const float* __restrict__ abias,
    const float* __restrict__ g, const float* __restrict__ be,
    unsigned short* __restrict__ xb)
{
    __shared__ float red[4];
    const long long r = blockIdx.x;
    const int d = threadIdx.x;
    const long long idx = r * DD + d;
    float v = x[idx] + a[idx];
    if (abias) v += abias[d];

    float s = v;
#pragma unroll
    for (int off = 32; off > 0; off >>= 1) s += __shfl_down(s, off);
    if ((d & 63) == 0) red[d >> 6] = s;
    __syncthreads();
    float mean = (red[0] + red[1] + red[2] + red[3]) * (1.f / DD);
    __syncthreads();

    float df = v - mean;
    float s2 = df * df;
#pragma unroll
    for (int off = 32; off > 0; off >>= 1) s2 += __shfl_down(s2, off);
    if ((d & 63) == 0) red[d >> 6] = s2;
    __syncthreads();
    float var = (red[0] + red[1] + red[2] + red[3]) * (1.f / DD);

    float o = df / sqrtf(var + 1e-5f) * g[d] + be[d];
    x[idx] = o;
    xb[idx] = f2bu(o);
}

// ---------------- small fp32 SGEMM for FFN ----------------
__global__ __launch_bounds__(256) void sgemm_small(
    const float* __restrict__ A, int lda,
    const float* __restrict__ Bm, int ldb,
    float* __restrict__ C, int ldc,
    int M, int N, int K, int mode, const float* __restrict__ bias)
{
    __shared__ float As[16][64];
    __shared__ float Bs[16][64];
    const int tid = threadIdx.x;
    const int tx = tid & 15, ty = tid >> 4;
    const int m0 = blockIdx.x * 64;
    const int n0 = blockIdx.y * 64;
    const int ar = tid >> 2, ak = (tid & 3) * 4;
    const int bk = tid >> 4, bn = (tid & 15) * 4;

    float acc[4][4];
#pragma unroll
    for (int i = 0; i < 4; ++i)
#pragma unroll
        for (int j = 0; j < 4; ++j) acc[i][j] = 0.f;

    for (int kt = 0; kt < K; kt += 16) {
        {
            const float4 va = *reinterpret_cast<const float4*>(
                A + (long long)(m0 + ar) * lda + (kt + ak));
            As[ak + 0][ar] = va.x; As[ak + 1][ar] = va.y;
            As[ak + 2][ar] = va.z; As[ak + 3][ar] = va.w;
        }
        {
            const float4 vb = *reinterpret_cast<const float4*>(
                Bm + (long long)(kt + bk) * ldb + (n0 + bn));
            *reinterpret_cast<float4*>(&Bs[bk][bn]) = vb;
        }
        __syncthreads();
#pragma unroll
        for (int k = 0; k < 16; ++k) {
            float a[4], b[4];
#pragma unroll
            for (int i = 0; i < 4; ++i) a[i] = As[k][ty + i * 16];
#pragma unroll
            for (int j = 0; j < 4; ++j) b[j] = Bs[k][tx + j * 16];
#pragma unroll
            for (int i = 0; i < 4; ++i)
#pragma unroll
                for (int j = 0; j < 4; ++j)
                    acc[i][j] = fmaf(a[i], b[j], acc[i][j]);
        }
        __syncthreads();
    }

#pragma unroll
    for (int i = 0; i < 4; ++i) {
        int r = m0 + ty + i * 16;
        float* crow = C + (long long)r * ldc;
#pragma unroll
        for (int j = 0; j < 4; ++j) {
            int n = n0 + tx + j * 16;
            float v = acc[i][j];
            if (mode >= 1) v += bias[n];
            if (mode == 2) v = 0.5f * v * (1.f + erff(v * 0.70710678118f));
            crow[n] = v;
        }
    }
}

// ---------------- launch ----------------
extern "C" void kernel_launch(void* const* d_in, const int* in_sizes, int n_in,
                              void* d_out, int out_size, void* d_ws, size_t ws_size,
                              hipStream_t stream)
{
    const int*   src_ids = (const int*)d_in[0];
    const int*   t1      = (const int*)d_in[1];
    const int*   t2      = (const int*)d_in[2];
    const float* enc  = (const float*)d_in[4];
    const float* emb  = (const float*)d_in[5];
    const float* Wq_s = (const float*)d_in[6];
    const float* Wk_s = (const float*)d_in[7];
    const float* Wv_s = (const float*)d_in[8];
    const float* Wo_s = (const float*)d_in[9];
    const float* bo_s = (const float*)d_in[10];
    const float* Wq_c = (const float*)d_in[11];
    const float* Wk_c = (const float*)d_in[12];
    const float* Wv_c = (const float*)d_in[13];
    const float* Wo_c = (const float*)d_in[14];
    const float* bo_c = (const float*)d_in[15];
    const float* W1   = (const float*)d_in[16];
    const float* b1   = (const float*)d_in[17];
    const float* W2   = (const float*)d_in[18];
    const float* b2   = (const float*)d_in[19];
    const float* g1   = (const float*)d_in[20];
    const float* g2v  = (const float*)d_in[21];
    const float* g3   = (const float*)d_in[22];
    const float* be1  = (const float*)d_in[23];
    const float* be2  = (const float*)d_in[24];
    const float* be3  = (const float*)d_in[25];
    const float* Wfc  = (const float*)d_in[26];
    const float* bfc  = (const float*)d_in[27];

    // ---------------- d_ws layout (~106 MB) ----------------
    char* p = (char*)d_ws;
    float* x    = (float*)p;           p += (size_t)ROWS * DD * 4;
    float* aout = (float*)p;           p += (size_t)ROWS * DD * 4;
    float* h1   = (float*)p;           p += (size_t)ROWS * DD * 4;
    unsigned short* xb   = (unsigned short*)p; p += (size_t)ROWS * DD * 2;
    unsigned short* xT   = (unsigned short*)p; p += (size_t)DD * ROWS * 2;   // [256][3072]
    unsigned short* encb = (unsigned short*)p; p += (size_t)SROWS * DD * 2;
    unsigned short* encT = (unsigned short*)p; p += (size_t)DD * SROWS * 2;  // [256][2048]
    unsigned short* Wqb_s = (unsigned short*)p; p += (size_t)DD * INNER_ * 2;  // 6 contiguous
    unsigned short* Wkb_s = (unsigned short*)p; p += (size_t)DD * INNER_ * 2;
    unsigned short* Wvb_s = (unsigned short*)p; p += (size_t)DD * INNER_ * 2;
    unsigned short* Wqb_c = (unsigned short*)p; p += (size_t)DD * INNER_ * 2;
    unsigned short* Wkb_c = (unsigned short*)p; p += (size_t)DD * INNER_ * 2;
    unsigned short* Wvb_c = (unsigned short*)p; p += (size_t)DD * INNER_ * 2;
    unsigned short* WoTs  = (unsigned short*)p; p += (size_t)DD * INNER_ * 2;
    unsigned short* WoTc  = (unsigned short*)p; p += (size_t)DD * INNER_ * 2;
    unsigned short* WfcT  = (unsigned short*)p; p += (size_t)VPAD * DD * 2;
    unsigned short* MtNb  = (unsigned short*)p; p += (size_t)4 * 524288 * 2;
    unsigned char* tgtpad = (unsigned char*)p; p += ROWS;
    unsigned char* srcpad = (unsigned char*)p; p += SROWS;
    p = (char*)(((size_t)p + 15) & ~(size_t)15);
    int* rowmap = (int*)p;             p += (size_t)ROWS * 4;

    unsigned short* Mtb_s = MtNb;
    unsigned short* Ntb_s = MtNb + 524288;
    unsigned short* Mtb_c = MtNb + 2 * 524288;
    unsigned short* Ntb_c = MtNb + 3 * 524288;

    // ---------------- d_out scratch (100.7 MB < 312 MB, dead before logits) ----
    unsigned short* ob = (unsigned short*)d_out;
    unsigned short* simS = ob;                    // [16][1536][1536] max (75.5 MB)
    unsigned short* Pb   = ob + 37748736;         // [8][3072][256]   (12.6 MB)
    unsigned short* Ub   = Pb + 6291456;          // [3072][2048]     (12.6 MB)
    float* MNacc = (float*)d_out;                 // [4][524288] f32, aliases simS (dead early)

    // ---------------- prep ----------------
    embed_kernel<<<dim3(TT, BB), 256, 0, stream>>>(t1, t2, emb, x, xb, tgtpad);
    masks_kernel<<<dim3(ROWS / 256), 256, 0, stream>>>(src_ids, srcpad, rowmap);
    conv_bf16v4<<<dim3((SROWS * DD) / 1024), 256, 0, stream>>>(enc, encb);

    dim3 tcb(32, 8);
    transpose_conv<<<dim3(ROWS / 32, 8), tcb, 0, stream>>>(x, xT, ROWS, DD, DD);
    transpose_conv<<<dim3(SROWS / 32, 8), tcb, 0, stream>>>(enc, encT, SROWS, DD, DD);
    convW6<<<dim3((DD * INNER_) / 1024, 6), 256, 0, stream>>>(
        Wq_s, Wk_s, Wv_s, Wq_c, Wk_c, Wv_c, Wqb_s);
    transpose_conv<<<dim3(512, 8), tcb, 0, stream>>>(Wo_s, WoTs, INNER_, DD, DD);
    transpose_conv<<<dim3(512, 8), tcb, 0, stream>>>(Wo_c, WoTc, INNER_, DD, DD);
    transpose_conv<<<dim3(8, VPAD / 32), tcb, 0, stream>>>(Wfc, WfcT, DD, VV, VPAD);

    const float scale = 0.022097086912079608f;  // DH^-0.5
    const long long Z0 = 0;

    // ---------------- M/N precompute (rank-256 folding) ----------------
    hipMemsetAsync(MNacc, 0, (size_t)4 * 524288 * 4, stream);
    gemm_bt<3, 4><<<dim3(2, 2, 32), 256, 0, stream>>>(
        Wkb_s, INNER_, Wqb_s, INNER_, MNacc, 256, 256, 256, DHD, 1.f, 0,
        Z0, 2048, Z0, 2048, Z0, 65536, nullptr, nullptr);
    gemm_bt<3, 4><<<dim3(2, 2, 32), 256, 0, stream>>>(
        WoTs, INNER_, Wvb_s, INNER_, MNacc + 524288, 2048, 256, 256, DHD, 1.f, 0,
        Z0, 2048, Z0, 2048, Z0, 256, nullptr, nullptr);
    gemm_bt<3, 4><<<dim3(2, 2, 32), 256, 0, stream>>>(
        Wkb_c, INNER_, Wqb_c, INNER_, MNacc + 2 * 524288, 256, 256, 256, DHD, 1.f, 0,
        Z0, 2048, Z0, 2048, Z0, 65536, nullptr, nullptr);
    gemm_bt<3, 4><<<dim3(2, 2, 32), 256, 0, stream>>>(
        WoTc, INNER_, Wvb_c, INNER_, MNacc + 3 * 524288, 2048, 256, 256, DHD, 1.f, 0,
        Z0, 2048, Z0, 2048, Z0, 256, nullptr, nullptr);
    conv_bf16v4<<<dim3((4 * 524288) / 1024), 256, 0, stream>>>(MNacc, MtNb);

    // ---------------- self attention ----------------
    hipMemsetAsync(aout, 0, (size_t)ROWS * DD * sizeof(float), stream);
    gemm_bt<0, 1><<<dim3(24, 2, 8), 256, 0, stream>>>(
        xb, DD, Mtb_s, DD, Pb, DD, ROWS, DD, DD, 1.f, 3,
        Z0, Z0, Z0, 65536, Z0, 786432, nullptr, nullptr);
    gemm_bt<0, 1><<<dim3(12, 12, 16), 256, 0, stream>>>(
        Pb, DD, xb, DD, simS, TT, TT, TT, DD, scale, 3,
        393216, 786432, 393216, Z0,
        18874368, 2359296, nullptr, nullptr);
    softmax_bf16<6><<<dim3(TT, 16), 256, 0, stream>>>(simS, tgtpad, 3);
    gemm_bt<0, 1><<<dim3(12, 2, 16), 256, 0, stream>>>(
        simS, TT, xT, ROWS, Ub, 2048, TT, DD, TT, 1.f, 3,
        18874368, 2359296, 1536, Z0,
        3145728, 256, nullptr, nullptr);
    gemm_bt<3, 4><<<dim3(24, 2, 4), 256, 0, stream>>>(
        Ub, 2048, Ntb_s, 2048, aout, DD, ROWS, DD, 2048, 1.f, 0,
        Z0, Z0, Z0, Z0, Z0, Z0, nullptr, nullptr);
    ln_kernel<<<dim3(ROWS), 256, 0, stream>>>(x, aout, bo_s, g1, be1, xb);

    // ---------------- cross attention ----------------
    hipMemsetAsync(aout, 0, (size_t)ROWS * DD * sizeof(float), stream);
    gemm_bt<0, 1><<<dim3(24, 2, 8), 256, 0, stream>>>(
        xb, DD, Mtb_c, DD, Pb, DD, ROWS, DD, DD, 1.f, 3,
        Z0, Z0, Z0, 65536, Z0, 786432, nullptr, nullptr);
    gemm_bt<0, 1><<<dim3(12, 8, 16), 256, 0, stream>>>(
        Pb, DD, encb, DD, simS, SS, TT, SS, DD, scale, 3,
        393216, 786432, 262144, Z0,
        12582912, 1572864, nullptr, nullptr);
    softmax_bf16<4><<<dim3(TT, 16), 256, 0, stream>>>(simS, srcpad, 3);
    gemm_bt<0, 1><<<dim3(12, 2, 16), 256, 0, stream>>>(
        simS, SS, encT, SROWS, Ub, 2048, TT, DD, SS, 1.f, 3,
        12582912, 1572864, 1024, Z0,
        3145728, 256, nullptr, nullptr);
    gemm_bt<3, 4><<<dim3(24, 2, 4), 256, 0, stream>>>(
        Ub, 2048, Ntb_c, 2048, aout, DD, ROWS, DD, 2048, 1.f, 0,
        Z0, Z0, Z0, Z0, Z0, Z0, nullptr, nullptr);
    ln_kernel<<<dim3(ROWS), 256, 0, stream>>>(x, aout, bo_c, g2v, be2, xb);

    // ---------------- FFN (D->D->D, exact GELU), fp32 ----------------
    sgemm_small<<<dim3(ROWS / 64, DD / 64, 1), 256, 0, stream>>>(
        x, DD, W1, DD, h1, DD, ROWS, DD, DD, 2, b1);
    sgemm_small<<<dim3(ROWS / 64, DD / 64, 1), 256, 0, stream>>>(
        h1, DD, W2, DD, aout, DD, ROWS, DD, DD, 0, nullptr);
    ln_kernel<<<dim3(ROWS), 256, 0, stream>>>(x, aout, b2, g3, be3, xb);

    // ---------------- logits (bf16 MFMA, rowmap drops t==0 rows) ----------------
    gemm_bt<2, 1><<<dim3(24, VPAD / 128, 1), 256, 0, stream>>>(
        xb, DD, WfcT, DD, d_out, VV, ROWS, VV, DD, 1.f, 0,
        Z0, Z0, Z0, Z0, Z0, Z0, bfc, rowmap);

    // ---------------- second output: x[:,0,:] ----------------
    copycls_kernel<<<dim3(BB), 256, 0, stream>>>(
        x, (float*)d_out + (long long)BB * (TT - 1) * VV);
}

// Round 8
// 634.356 us; speedup vs baseline: 27.0192x; 1.0074x over previous
//
#include <hip/hip_runtime.h>
#include <hip/hip_bf16.h>
#include <float.h>
#include <math.h>

// ---------------- problem constants ----------------
#define BB 2
#define SS 1024
#define LL 767
#define TT 1536          // 2*(LL+1)
#define DD 256
#define HH 8
#define DHD 2048
#define INNER_ 16384
#define VV 25426
#define VPAD 25472
#define CLS_TOK 25426
#define MASK_TOKEN 25428
#define ROWS (BB*TT)     // 3072
#define SROWS (BB*SS)    // 2048

typedef __attribute__((ext_vector_type(8))) __bf16 bf16x8;
typedef __attribute__((ext_vector_type(4))) float f32x4;

__device__ __forceinline__ unsigned short f2bu(float f) {
    union { float f; unsigned u; } v; v.f = f;
    unsigned r = v.u + 0x7fff + ((v.u >> 16) & 1);
    return (unsigned short)(r >> 16);
}
__device__ __forceinline__ float bu2f(unsigned short u) {
    union { unsigned u; float f; } v; v.u = ((unsigned)u) << 16;
    return v.f;
}

__device__ __forceinline__ void gload16(const void* g, void* l) {
    __builtin_amdgcn_global_load_lds(
        (const __attribute__((address_space(1))) void*)g,
        (__attribute__((address_space(3))) void*)l, 16, 0, 0);
}

// ---------------- small helper kernels ----------------

__global__ __launch_bounds__(256) void embed_kernel(
    const int* __restrict__ t1, const int* __restrict__ t2,
    const float* __restrict__ emb, float* __restrict__ x,
    unsigned short* __restrict__ xb, unsigned char* __restrict__ tgt_pad)
{
    int t = blockIdx.x, b = blockIdx.y, d = threadIdx.x;
    int raw;
    if (t == 0)            raw = CLS_TOK;
    else if (t <= LL)      raw = t1[b * LL + (t - 1)];
    else if (t == LL + 1)  raw = CLS_TOK;
    else                   raw = t2[b * LL + (t - LL - 2)];
    int id = (raw == 0 || raw == MASK_TOKEN) ? MASK_TOKEN : raw;
    int i = d >> 1;
    float ang = (float)t * expf(-0.03597789208f * (float)(2 * i));
    float pe = (d & 1) ? cosf(ang) : sinf(ang);
    float val = 2.f * emb[(long long)id * DD + d] + pe;
    long long idx = ((long long)(b * TT + t)) * DD + d;
    x[idx] = val;
    xb[idx] = f2bu(val);
    if (d == 0) tgt_pad[b * TT + t] = (raw == 0) ? 1 : 0;
}

// src pad mask + rowmap in one launch (grid ROWS/256)
__global__ __launch_bounds__(256) void masks_kernel(
    const int* __restrict__ src, unsigned char* __restrict__ m, int* __restrict__ rm)
{
    int i = blockIdx.x * 256 + threadIdx.x;
    if (i < SROWS) m[i] = (src[i] == 0) ? 1 : 0;
    if (i < ROWS) {
        int b = i / TT, t = i % TT;
        rm[i] = (t == 0) ? -1 : (b * (TT - 1) + t - 1);
    }
}

__global__ __launch_bounds__(256) void copycls_kernel(
    const float* __restrict__ x, float* __restrict__ out2)
{
    int b = blockIdx.x, d = threadIdx.x;
    out2[b * DD + d] = x[(long long)b * TT * DD + d];
}

// vectorized f32 -> bf16 convert (4 elems/thread); n % 1024 == 0
__global__ __launch_bounds__(256) void conv_bf16v4(
    const float* __restrict__ in, unsigned short* __restrict__ out)
{
    size_t i = ((size_t)blockIdx.x * 256 + threadIdx.x) * 4;
    float4 v = *reinterpret_cast<const float4*>(in + i);
    ushort4 u;
    u.x = f2bu(v.x); u.y = f2bu(v.y); u.z = f2bu(v.z); u.w = f2bu(v.w);
    *reinterpret_cast<ushort4*>(out + i) = u;
}

// six weight matrices [DD][INNER_] f32 -> contiguous bf16 (one launch)
__global__ __launch_bounds__(256) void convW6(
    const float* __restrict__ w0, const float* __restrict__ w1,
    const float* __restrict__ w2, const float* __restrict__ w3,
    const float* __restrict__ w4, const float* __restrict__ w5,
    unsigned short* __restrict__ dst)
{
    int seg = blockIdx.y;
    const float* s = seg == 0 ? w0 : seg == 1 ? w1 : seg == 2 ? w2 :
                     seg == 3 ? w3 : seg == 4 ? w4 : w5;
    size_t i = ((size_t)blockIdx.x * 256 + threadIdx.x) * 4;
    float4 v = *reinterpret_cast<const float4*>(s + i);
    ushort4 u;
    u.x = f2bu(v.x); u.y = f2bu(v.y); u.z = f2bu(v.z); u.w = f2bu(v.w);
    *reinterpret_cast<ushort4*>(dst + (size_t)seg * ((size_t)DD * INNER_) + i) = u;
}

// transpose + convert: out[n][k] = bf16(in[k][n]); in [R][Cin] f32, out [Nout][R] bf16.
__global__ __launch_bounds__(256) void transpose_conv(
    const float* __restrict__ in, unsigned short* __restrict__ out,
    int R, int Cin, int Nout)
{
    __shared__ float t[32][33];
    int k0 = blockIdx.x * 32, n0 = blockIdx.y * 32;
#pragma unroll
    for (int i = 0; i < 4; ++i) {
        int k = k0 + threadIdx.y + i * 8;
        int n = n0 + threadIdx.x;
        t[threadIdx.y + i * 8][threadIdx.x] = (n < Cin) ? in[(size_t)k * Cin + n] : 0.f;
    }
    __syncthreads();
#pragma unroll
    for (int i = 0; i < 4; ++i) {
        int n = n0 + threadIdx.y + i * 8;
        int k = k0 + threadIdx.x;
        out[(size_t)n * R + k] = f2bu(t[threadIdx.x][threadIdx.y + i * 8]);
    }
}

// ---------------- bf16 MFMA GEMM (BT form, z-batched, BK=64) ----------------
// C[M,N] = alpha * A[M,K] * B[N,K]^T. A,B bf16 row-major, K-contiguous.
// 128x128 tile, BK=64, 4 waves, global_load_lds with 8-slot XOR swizzle.
// SPLITK==1: zb = z>>zs, zh = z & ((1<<zs)-1); offsets zb*s?b + zh*s?h.
// SPLITK>1 (pow2): kidx = z & (SPLITK-1), zh = z>>log2(SPLITK); K-chunk = kidx.
// Requires M%128==0, (K/SPLITK)%64==0, lda/ldb%8==0, bases 16B-aligned.
// STORE: 0 = bf16 C (+czoff); 1 = bf16 C^T (C[c*ldc+r], packed 8B, +czoff);
//        2 = fp32 C + bias + rowmap + col guard; 3 = fp32 atomicAdd (+czoff);
//        4 = bf16 C with bias + exact GELU (+czoff); 5 = fp32 C plain (+czoff).
template<int STORE, int SPLITK>
__global__ __launch_bounds__(256) void gemm_bt(
    const unsigned short* __restrict__ A, int lda,
    const unsigned short* __restrict__ B, int ldb,
    void* __restrict__ Cv, int ldc,
    int M, int N, int K, float alpha, int zs,
    long long sAb, long long sAh, long long sBb, long long sBh,
    long long sCb, long long sCh,
    const float* __restrict__ bias, const int* __restrict__ rowmap)
{
    __shared__ unsigned short As[8192];  // 128 rows x 64 k (16 KB), slot-swizzled
    __shared__ unsigned short Bs[8192];
    const int tid = threadIdx.x;
    const int w = tid >> 6, l = tid & 63;
    const int m0 = blockIdx.x * 128, n0 = blockIdx.y * 128;

    int kbeg = 0, kend = K;
    long long czoff = 0;
    if (SPLITK > 1) {
        constexpr int KSH = (SPLITK == 8) ? 3 : (SPLITK == 4) ? 2 : (SPLITK == 2) ? 1 : 0;
        int kidx = blockIdx.z & (SPLITK - 1);
        int zh = blockIdx.z >> KSH;
        int kc = K / SPLITK;
        kbeg = kidx * kc; kend = kbeg + kc;
        A += zh * sAh;
        B += zh * sBh;
        czoff = zh * sCh;
    } else {
        int zb = blockIdx.z >> zs;
        int zh = blockIdx.z - (zb << zs);
        A += zb * sAb + zh * sAh;
        B += zb * sBb + zh * sBh;
        czoff = zb * sCb + zh * sCh;
    }

    const int wr = (w >> 1) << 6, wc = (w & 1) << 6;
    const int lrow = l & 15, lk = l >> 4;

    // staging: round j writes LDS byte j*4096 + w*1024 + l*16.
    // row = off>>7 = j*32 + w*8 + (l>>3); lds slot = l&7;
    // global slot = (l&7) ^ (row&7) = (l&7) ^ (l>>3)
    const int sro = (w << 3) + (l >> 3);
    const int sko = (((l & 7) ^ (l >> 3)) << 3);
    const int ldst = (w << 10) + (l << 4);

    f32x4 acc[4][4];
#pragma unroll
    for (int mi = 0; mi < 4; ++mi)
#pragma unroll
        for (int ni = 0; ni < 4; ++ni)
            acc[mi][ni] = (f32x4){0.f, 0.f, 0.f, 0.f};

    for (int kt = kbeg; kt < kend; kt += 64) {
#pragma unroll
        for (int j = 0; j < 4; ++j)
            gload16(A + (size_t)(m0 + sro + j * 32) * lda + kt + sko,
                    (char*)As + (j << 12) + ldst);
#pragma unroll
        for (int j = 0; j < 4; ++j)
            gload16(B + (size_t)(n0 + sro + j * 32) * ldb + kt + sko,
                    (char*)Bs + (j << 12) + ldst);
        __syncthreads();

#pragma unroll
        for (int kk = 0; kk < 2; ++kk) {
            const int slot = (kk << 2) + lk;
            bf16x8 af[4], bfr[4];
#pragma unroll
            for (int mi = 0; mi < 4; ++mi) {
                int ra = wr + (mi << 4) + lrow;
                af[mi] = *reinterpret_cast<const bf16x8*>(
                    (const char*)As + (ra << 7) + ((slot ^ (ra & 7)) << 4));
            }
#pragma unroll
            for (int ni = 0; ni < 4; ++ni) {
                int rb = wc + (ni << 4) + lrow;
                bfr[ni] = *reinterpret_cast<const bf16x8*>(
                    (const char*)Bs + (rb << 7) + ((slot ^ (rb & 7)) << 4));
            }
#pragma unroll
            for (int mi = 0; mi < 4; ++mi)
#pragma unroll
                for (int ni = 0; ni < 4; ++ni)
                    acc[mi][ni] = __builtin_amdgcn_mfma_f32_16x16x32_bf16(
                        af[mi], bfr[ni], acc[mi][ni], 0, 0, 0);
        }
        __syncthreads();
    }

    // C/D layout: col = lane&15, row = (lane>>4)*4 + reg
    if (STORE == 0) {
        unsigned short* C = (unsigned short*)Cv + czoff;
#pragma unroll
        for (int mi = 0; mi < 4; ++mi) {
            int r = m0 + wr + (mi << 4) + (lk << 2);
#pragma unroll
            for (int ni = 0; ni < 4; ++ni) {
                int c = n0 + wc + (ni << 4) + lrow;
#pragma unroll
                for (int q = 0; q < 4; ++q)
                    C[(size_t)(r + q) * ldc + c] = f2bu(acc[mi][ni][q] * alpha);
            }
        }
    } else if (STORE == 1) {
        unsigned short* C = (unsigned short*)Cv + czoff;
#pragma unroll
        for (int ni = 0; ni < 4; ++ni) {
            int c = n0 + wc + (ni << 4) + lrow;
#pragma unroll
            for (int mi = 0; mi < 4; ++mi) {
                int r = m0 + wr + (mi << 4) + (lk << 2);
                ushort4 u;
                u.x = f2bu(acc[mi][ni][0] * alpha);
                u.y = f2bu(acc[mi][ni][1] * alpha);
                u.z = f2bu(acc[mi][ni][2] * alpha);
                u.w = f2bu(acc[mi][ni][3] * alpha);
                *reinterpret_cast<ushort4*>(&C[(size_t)c * ldc + r]) = u;
            }
        }
    } else if (STORE == 2) {
        float* C = (float*)Cv;
#pragma unroll
        for (int mi = 0; mi < 4; ++mi) {
            int r = m0 + wr + (mi << 4) + (lk << 2);
#pragma unroll
            for (int q = 0; q < 4; ++q) {
                int rm = rowmap[r + q];
                if (rm < 0) continue;
#pragma unroll
                for (int ni = 0; ni < 4; ++ni) {
                    int c = n0 + wc + (ni << 4) + lrow;
                    if (c < N) C[(size_t)rm * ldc + c] = acc[mi][ni][q] * alpha + bias[c];
                }
            }
        }
    } else if (STORE == 3) {
        float* C = (float*)Cv + czoff;
#pragma unroll
        for (int mi = 0; mi < 4; ++mi) {
            int r = m0 + wr + (mi << 4) + (lk << 2);
#pragma unroll
            for (int ni = 0; ni < 4; ++ni) {
                int c = n0 + wc + (ni << 4) + lrow;
#pragma unroll
                for (int q = 0; q < 4; ++q)
                    atomicAdd(&C[(size_t)(r + q) * ldc + c], acc[mi][ni][q] * alpha);
            }
        }
    } else if (STORE == 4) {
        unsigned short* C = (unsigned short*)Cv + czoff;
#pragma unroll
        for (int mi = 0; mi < 4; ++mi) {
            int r = m0 + wr + (mi << 4) + (lk << 2);
#pragma unroll
            for (int ni = 0; ni < 4; ++ni) {
                int c = n0 + wc + (ni << 4) + lrow;
#pragma unroll
                for (int q = 0; q < 4; ++q) {
                    float v = acc[mi][ni][q] * alpha + bias[c];
                    v = 0.5f * v * (1.f + erff(v * 0.70710678118f));
                    C[(size_t)(r + q) * ldc + c] = f2bu(v);
                }
            }
        }
    } else {
        float* C = (float*)Cv + czoff;
#pragma unroll
        for (int mi = 0; mi < 4; ++mi) {
            int r = m0 + wr + (mi << 4) + (lk << 2);
#pragma unroll
            for (int ni = 0; ni < 4; ++ni) {
                int c = n0 + wc + (ni << 4) + lrow;
#pragma unroll
                for (int q = 0; q < 4; ++q)
                    C[(size_t)(r + q) * ldc + c] = acc[mi][ni][q] * alpha;
            }
        }
    }
}

// ---------------- masked row softmax on bf16, z-batched, ushort2-vectorized ----
// row length = PPT*512 elems (PPT pairs per thread); mask per batch b = z>>zs.
template<int PPT>
__global__ __launch_bounds__(256) void softmax_bf16(
    unsigned short* __restrict__ S, const unsigned char* __restrict__ mask, int zs)
{
    __shared__ float red[4];
    const int z = blockIdx.y;
    const int RL = PPT * 512;
    ushort2* p = (ushort2*)(S + ((long long)z * TT + blockIdx.x) * RL);
    const uchar2* mk = (const uchar2*)(mask + (long long)(z >> zs) * RL);
    const int tid = threadIdx.x;

    float v[2 * PPT];
    float mx = -FLT_MAX;
#pragma unroll
    for (int c = 0; c < PPT; ++c) {
        int j = (c << 8) + tid;
        ushort2 u = p[j];
        uchar2 mm = mk[j];
        float s0 = mm.x ? -FLT_MAX : bu2f(u.x);
        float s1 = mm.y ? -FLT_MAX : bu2f(u.y);
        v[2 * c] = s0; v[2 * c + 1] = s1;
        mx = fmaxf(mx, fmaxf(s0, s1));
    }
#pragma unroll
    for (int off = 32; off > 0; off >>= 1) mx = fmaxf(mx, __shfl_down(mx, off));
    if ((tid & 63) == 0) red[tid >> 6] = mx;
    __syncthreads();
    mx = fmaxf(fmaxf(red[0], red[1]), fmaxf(red[2], red[3]));
    __syncthreads();

    float sum = 0.f;
#pragma unroll
    for (int c = 0; c < 2 * PPT; ++c) {
        float e = expf(v[c] - mx);
        v[c] = e;
        sum += e;
    }
#pragma unroll
    for (int off = 32; off > 0; off >>= 1) sum += __shfl_down(sum, off);
    if ((tid & 63) == 0) red[tid >> 6] = sum;
    __syncthreads();
    sum = red[0] + red[1] + red[2] + red[3];
    float inv = 1.f / sum;
#pragma unroll
    for (int c = 0; c < PPT; ++c) {
        int j = (c << 8) + tid;
        ushort2 u;
        u.x = f2bu(v[2 * c] * inv);
        u.y = f2bu(v[2 * c + 1] * inv);
        p[j] = u;
    }
}

// ---------------- residual + LayerNorm (in place on x, emits bf16 copy) ----------------
__global__ __launch_bounds__(256) void ln_kernel(
    float* __restrict__ x, const float* __restrict__ a,
    const float* __restrict__ abias,
    const float* __restrict__ g, const float* __restrict__ be,
    unsigned short* __restrict__ xb)
{
    __shared__ float red[4];
    const long long r = blockIdx.x;
    const int d = threadIdx.x;
    const long long idx = r * DD + d;
    float v = x[idx] + a[idx];
    if (abias) v += abias[d];

    float s = v;
#pragma unroll
    for (int off = 32; off > 0; off >>= 1) s += __shfl_down(s, off);
    if ((d & 63) == 0) red[d >> 6] = s;
    __syncthreads();
    float mean = (red[0] + red[1] + red[2] + red[3]) * (1.f / DD);
    __syncthreads();

    float df = v - mean;
    float s2 = df * df;
#pragma unroll
    for (int off = 32; off > 0; off >>= 1) s2 += __shfl_down(s2, off);
    if ((d & 63) == 0) red[d >> 6] = s2;
    __syncthreads();
    float var = (red[0] + red[1] + red[2] + red[3]) * (1.f / DD);

    float o = df / sqrtf(var + 1e-5f) * g[d] + be[d];
    x[idx] = o;
    xb[idx] = f2bu(o);
}

// ---------------- launch ----------------
extern "C" void kernel_launch(void* const* d_in, const int* in_sizes, int n_in,
                              void* d_out, int out_size, void* d_ws, size_t ws_size,
                              hipStream_t stream)
{
    const int*   src_ids = (const int*)d_in[0];
    const int*   t1      = (const int*)d_in[1];
    const int*   t2      = (const int*)d_in[2];
    const float* enc  = (const float*)d_in[4];
    const float* emb  = (const float*)d_in[5];
    const float* Wq_s = (const float*)d_in[6];
    const float* Wk_s = (const float*)d_in[7];
    const float* Wv_s = (const float*)d_in[8];
    const float* Wo_s = (const float*)d_in[9];
    const float* bo_s = (const float*)d_in[10];
    const float* Wq_c = (const float*)d_in[11];
    const float* Wk_c = (const float*)d_in[12];
    const float* Wv_c = (const float*)d_in[13];
    const float* Wo_c = (const float*)d_in[14];
    const float* bo_c = (const float*)d_in[15];
    const float* W1   = (const float*)d_in[16];
    const float* b1   = (const float*)d_in[17];
    const float* W2   = (const float*)d_in[18];
    const float* b2   = (const float*)d_in[19];
    const float* g1   = (const float*)d_in[20];
    const float* g2v  = (const float*)d_in[21];
    const float* g3   = (const float*)d_in[22];
    const float* be1  = (const float*)d_in[23];
    const float* be2  = (const float*)d_in[24];
    const float* be3  = (const float*)d_in[25];
    const float* Wfc  = (const float*)d_in[26];
    const float* bfc  = (const float*)d_in[27];

    // ---------------- d_ws layout (~85 MB) ----------------
    char* p = (char*)d_ws;
    float* x    = (float*)p;           p += (size_t)ROWS * DD * 4;
    float* aout = (float*)p;           p += (size_t)ROWS * DD * 4;
    unsigned short* h1b  = (unsigned short*)p; p += (size_t)ROWS * DD * 2;
    unsigned short* xb   = (unsigned short*)p; p += (size_t)ROWS * DD * 2;
    unsigned short* encb = (unsigned short*)p; p += (size_t)SROWS * DD * 2;
    unsigned short* Wqb_s = (unsigned short*)p; p += (size_t)DD * INNER_ * 2;  // 6 contiguous
    unsigned short* Wkb_s = (unsigned short*)p; p += (size_t)DD * INNER_ * 2;
    unsigned short* Wvb_s = (unsigned short*)p; p += (size_t)DD * INNER_ * 2;
    unsigned short* Wqb_c = (unsigned short*)p; p += (size_t)DD * INNER_ * 2;
    unsigned short* Wkb_c = (unsigned short*)p; p += (size_t)DD * INNER_ * 2;
    unsigned short* Wvb_c = (unsigned short*)p; p += (size_t)DD * INNER_ * 2;
    unsigned short* WoTs  = (unsigned short*)p; p += (size_t)DD * INNER_ * 2;
    unsigned short* WoTc  = (unsigned short*)p; p += (size_t)DD * INNER_ * 2;
    unsigned short* WfcT  = (unsigned short*)p; p += (size_t)VPAD * DD * 2;
    unsigned short* W1Tb  = (unsigned short*)p; p += (size_t)DD * DD * 2;
    unsigned short* W2Tb  = (unsigned short*)p; p += (size_t)DD * DD * 2;
    unsigned short* MtNb  = (unsigned short*)p; p += (size_t)4 * 524288 * 2;
    unsigned char* tgtpad = (unsigned char*)p; p += ROWS;
    unsigned char* srcpad = (unsigned char*)p; p += SROWS;
    p = (char*)(((size_t)p + 15) & ~(size_t)15);
    int* rowmap = (int*)p;             p += (size_t)ROWS * 4;

    unsigned short* Mtb_s = MtNb;
    unsigned short* Ntb_s = MtNb + 524288;
    unsigned short* Mtb_c = MtNb + 2 * 524288;
    unsigned short* Ntb_c = MtNb + 3 * 524288;

    // ---------------- d_out scratch (100.7 MB < 312 MB, dead before logits) ----
    unsigned short* ob = (unsigned short*)d_out;
    unsigned short* simS = ob;                    // [16][1536][1536] max (75.5 MB)
    unsigned short* Pb   = ob + 37748736;         // [8][3072][256]   (12.6 MB)
    unsigned short* YTb  = Pb + 6291456;          // [8][256][3072]   (12.6 MB)
    float* MNacc = (float*)d_out;                 // [4][524288] f32, aliases simS (dead early)

    // ---------------- prep ----------------
    embed_kernel<<<dim3(TT, BB), 256, 0, stream>>>(t1, t2, emb, x, xb, tgtpad);
    masks_kernel<<<dim3(ROWS / 256), 256, 0, stream>>>(src_ids, srcpad, rowmap);
    conv_bf16v4<<<dim3((SROWS * DD) / 1024), 256, 0, stream>>>(enc, encb);

    dim3 tcb(32, 8);
    convW6<<<dim3((DD * INNER_) / 1024, 6), 256, 0, stream>>>(
        Wq_s, Wk_s, Wv_s, Wq_c, Wk_c, Wv_c, Wqb_s);
    transpose_conv<<<dim3(512, 8), tcb, 0, stream>>>(Wo_s, WoTs, INNER_, DD, DD);
    transpose_conv<<<dim3(512, 8), tcb, 0, stream>>>(Wo_c, WoTc, INNER_, DD, DD);
    transpose_conv<<<dim3(8, VPAD / 32), tcb, 0, stream>>>(Wfc, WfcT, DD, VV, VPAD);
    transpose_conv<<<dim3(8, 8), tcb, 0, stream>>>(W1, W1Tb, DD, DD, DD);
    transpose_conv<<<dim3(8, 8), tcb, 0, stream>>>(W2, W2Tb, DD, DD, DD);

    const float scale = 0.022097086912079608f;  // DH^-0.5
    const long long Z0 = 0;

    // ---------------- M/N precompute (rank-256 folding) ----------------
    // Mt stored: Mt[r][h*256+c] = M_h... (P = x @ Mt^T per head)
    // Nt stored: Nt[r][h*256+c] = N_h[c][r], N_h = Wv_h @ Wo_h
    hipMemsetAsync(MNacc, 0, (size_t)4 * 524288 * 4, stream);
    gemm_bt<3, 4><<<dim3(2, 2, 32), 256, 0, stream>>>(
        Wkb_s, INNER_, Wqb_s, INNER_, MNacc, 256, 256, 256, DHD, 1.f, 0,
        Z0, 2048, Z0, 2048, Z0, 65536, nullptr, nullptr);
    gemm_bt<3, 4><<<dim3(2, 2, 32), 256, 0, stream>>>(
        WoTs, INNER_, Wvb_s, INNER_, MNacc + 524288, 2048, 256, 256, DHD, 1.f, 0,
        Z0, 2048, Z0, 2048, Z0, 256, nullptr, nullptr);
    gemm_bt<3, 4><<<dim3(2, 2, 32), 256, 0, stream>>>(
        Wkb_c, INNER_, Wqb_c, INNER_, MNacc + 2 * 524288, 256, 256, 256, DHD, 1.f, 0,
        Z0, 2048, Z0, 2048, Z0, 65536, nullptr, nullptr);
    gemm_bt<3, 4><<<dim3(2, 2, 32), 256, 0, stream>>>(
        WoTc, INNER_, Wvb_c, INNER_, MNacc + 3 * 524288, 2048, 256, 256, DHD, 1.f, 0,
        Z0, 2048, Z0, 2048, Z0, 256, nullptr, nullptr);
    conv_bf16v4<<<dim3((4 * 524288) / 1024), 256, 0, stream>>>(MNacc, MtNb);

    // ---------------- self attention ----------------
    hipMemsetAsync(aout, 0, (size_t)ROWS * DD * sizeof(float), stream);
    // P_h = x @ Mt_h^T : [8][3072][256]
    gemm_bt<0, 1><<<dim3(24, 2, 8), 256, 0, stream>>>(
        xb, DD, Mtb_s, DD, Pb, DD, ROWS, DD, DD, 1.f, 3,
        Z0, Z0, Z0, 65536, Z0, 786432, nullptr, nullptr);
    // Y_h = x @ N_h, stored transposed: YT[8][256][3072]
    gemm_bt<1, 1><<<dim3(24, 2, 8), 256, 0, stream>>>(
        xb, DD, Ntb_s, 2048, YTb, ROWS, ROWS, DD, DD, 1.f, 3,
        Z0, Z0, Z0, 256, Z0, 786432, nullptr, nullptr);
    // sim = P_h @ x^T : z=(b,h), [16][1536][1536]
    gemm_bt<0, 1><<<dim3(12, 12, 16), 256, 0, stream>>>(
        Pb, DD, xb, DD, simS, TT, TT, TT, DD, scale, 3,
        393216, 786432, 393216, Z0,
        18874368, 2359296, nullptr, nullptr);
    softmax_bf16<3><<<dim3(TT, 16), 256, 0, stream>>>(simS, tgtpad, 3);
    // O += attn_h @ Y_h : atomic fp32 into aout
    gemm_bt<3, 1><<<dim3(12, 2, 16), 256, 0, stream>>>(
        simS, TT, YTb, ROWS, aout, DD, TT, DD, TT, 1.f, 3,
        18874368, 2359296, 1536, 786432,
        393216, Z0, nullptr, nullptr);
    ln_kernel<<<dim3(ROWS), 256, 0, stream>>>(x, aout, bo_s, g1, be1, xb);

    // ---------------- cross attention ----------------
    hipMemsetAsync(aout, 0, (size_t)ROWS * DD * sizeof(float), stream);
    gemm_bt<0, 1><<<dim3(24, 2, 8), 256, 0, stream>>>(
        xb, DD, Mtb_c, DD, Pb, DD, ROWS, DD, DD, 1.f, 3,
        Z0, Z0, Z0, 65536, Z0, 786432, nullptr, nullptr);
    // Y_h = enc @ N_h, transposed: YT[8][256][2048]
    gemm_bt<1, 1><<<dim3(16, 2, 8), 256, 0, stream>>>(
        encb, DD, Ntb_c, 2048, YTb, SROWS, SROWS, DD, DD, 1.f, 3,
        Z0, Z0, Z0, 256, Z0, 524288, nullptr, nullptr);
    gemm_bt<0, 1><<<dim3(12, 8, 16), 256, 0, stream>>>(
        Pb, DD, encb, DD, simS, SS, TT, SS, DD, scale, 3,
        393216, 786432, 262144, Z0,
        12582912, 1572864, nullptr, nullptr);
    softmax_bf16<2><<<dim3(TT, 16), 256, 0, stream>>>(simS, srcpad, 3);
    gemm_bt<3, 1><<<dim3(12, 2, 16), 256, 0, stream>>>(
        simS, SS, YTb, SROWS, aout, DD, TT, DD, SS, 1.f, 3,
        12582912, 1572864, 1024, 524288,
        393216, Z0, nullptr, nullptr);
    ln_kernel<<<dim3(ROWS), 256, 0, stream>>>(x, aout, bo_c, g2v, be2, xb);

    // ---------------- FFN (D->D->D, exact GELU), bf16 MFMA ----------------
    gemm_bt<4, 1><<<dim3(24, 2, 1), 256, 0, stream>>>(
        xb, DD, W1Tb, DD, h1b, DD, ROWS, DD, DD, 1.f, 0,
        Z0, Z0, Z0, Z0, Z0, Z0, b1, nullptr);
    gemm_bt<5, 1><<<dim3(24, 2, 1), 256, 0, stream>>>(
        h1b, DD, W2Tb, DD, aout, DD, ROWS, DD, DD, 1.f, 0,
        Z0, Z0, Z0, Z0, Z0, Z0, nullptr, nullptr);
    ln_kernel<<<dim3(ROWS), 256, 0, stream>>>(x, aout, b2, g3, be3, xb);

    // ---------------- logits (bf16 MFMA, rowmap drops t==0 rows) ----------------
    gemm_bt<2, 1><<<dim3(24, VPAD / 128, 1), 256, 0, stream>>>(
        xb, DD, WfcT, DD, d_out, VV, ROWS, VV, DD, 1.f, 0,
        Z0, Z0, Z0, Z0, Z0, Z0, bfc, rowmap);

    // ---------------- second output: x[:,0,:] ----------------
    copycls_kernel<<<dim3(BB), 256, 0, stream>>>(
        x, (float*)d_out + (long long)BB * (TT - 1) * VV);
}